// Round 13
// baseline (955.250 us; speedup 1.0000x reference)
//
#include <hip/hip_runtime.h>

constexpr int N = 50000;
constexpr int G = 64;
constexpr int HID = 128;
constexpr int OUT = 768;
constexpr int MPAD = 50048;  // 391*128: GEMM A-tile reads never leave the buffer

typedef unsigned short u16;
typedef short s16x8 __attribute__((ext_vector_type(8)));
typedef float f32x4 __attribute__((ext_vector_type(4)));

__device__ inline float b2f(u16 b) { return __uint_as_float(((unsigned)b) << 16); }
__device__ inline u16 f2b(float f) {
    unsigned u = __float_as_uint(f);
    u += 0x7fff + ((u >> 16) & 1);   // round-to-nearest-even
    return (u16)(u >> 16);
}

__device__ inline void gload16(const void* g, void* l) {
    __builtin_amdgcn_global_load_lds((const __attribute__((address_space(1))) void*)g,
                                     (__attribute__((address_space(3))) void*)l, 16, 0, 0);
}

// ---------------- fused prep: input-transform ∥ edge-count ∥ weight-convert (independent work) ----
__global__ void prep_k(const float* __restrict__ x, const int* __restrict__ ids,
                       const float* __restrict__ emb, const float* __restrict__ inW,
                       const float* __restrict__ inb, u16* __restrict__ h,
                       const int* __restrict__ ei, int* __restrict__ cnt, int E, int ET, int nbCnt,
                       const float* __restrict__ lin0, const float* __restrict__ res0, u16* __restrict__ w0,
                       const float* __restrict__ lin1, const float* __restrict__ res1, u16* __restrict__ w1,
                       const float* __restrict__ lin2, const float* __restrict__ res2, u16* __restrict__ w2) {
    int b = blockIdx.x, t = threadIdx.x;
    if (b < 25000) {
        int idx = b * 256 + t;           // < N*HID = 6.4M exactly
        int i = idx >> 7, j = idx & 127;
        float s = inb[j] + emb[(size_t)ids[i] * HID + j];
        const float* xr = x + (size_t)i * 16;
#pragma unroll
        for (int k = 0; k < 16; ++k) s += xr[k] * inW[k * HID + j];
        h[idx] = f2b(s);
    } else if (b < 25000 + nbCnt) {
        int e = (b - 25000) * 256 + t;
        if (e < ET) {
            int d = (e < E) ? ei[E + e] : (e - E);
            atomicAdd(&cnt[d], 1);
        }
    } else {
        int i = (b - 25000 - nbCnt) * 256 + t;
        const float* lin; const float* res; u16* dst; int p, od;
        if (i < 131072)      { lin = lin0; res = res0; dst = w0; p = 128; od = 512; }
        else if (i < 655360) { lin = lin1; res = res1; dst = w1; p = 512; od = 512; i -= 131072; }
        else if (i < 786432) { lin = lin2; res = res2; dst = w2; p = 512; od = 128; i -= 655360; }
        else return;
        int o = i / p, k = i - o * p;
        float v = (o < od) ? lin[(size_t)k * od + o] : res[(size_t)k * od + (o - od)];
        dst[i] = f2b(v);
    }
}

// ---------------- fused MFMA GEMM with m-loop: [xl | rr] = A @ [linW | resW]^T, + scores ----------------
// BM=128, BN=128 (of 2*od), BK=32, 4 waves, 4x4 frags (round-9 verified geometry).
// Each block keeps its col-block and iterates TPB row-tiles; the next tile's first stage is
// issued BEFORE the epilogue so C-write/scores hide the prologue (short-K amortization).
template<int LAYER, int H, int TPB>
__global__ __launch_bounds__(256) void gemm2_k(const u16* __restrict__ A, const u16* __restrict__ Bt,
                                               const float* __restrict__ res_b,
                                               const float* __restrict__ a_s, const float* __restrict__ a_d,
                                               u16* __restrict__ xl, u16* __restrict__ rr,
                                               float* __restrict__ ssrc, float* __restrict__ sdst,
                                               int M, int od, int K) {
    __shared__ __align__(16) u16 lds[2][2][4096];  // [buf][A/B][128 rows * 32 k]
    __shared__ float sred[2][128][2];              // scores cross-wave reduce (no aliasing)
    int tid = threadIdx.x;
    int nbx = od >> 6;                 // (2*od)/128 col blocks
    // bijective XCD swizzle (m204)
    int nwg = gridDim.x;
    int qq = nwg >> 3, r8 = nwg & 7;
    int xcd = blockIdx.x & 7, ii = blockIdx.x >> 3;
    int swz = (xcd < r8 ? xcd * (qq + 1) : r8 * (qq + 1) + (xcd - r8) * qq) + ii;
    int bx = swz % nbx, chunk = swz / nbx;
    int col0 = bx << 7;
    int totTiles = (M + 127) >> 7;     // 391
    int by0 = chunk * TPB;
    if (by0 >= totTiles) return;
    int ntiles = totTiles - by0; if (ntiles > TPB) ntiles = TPB;
    int wave = tid >> 6, lane = tid & 63;
    int wm = (wave & 1) << 6, wn = (wave >> 1) << 6;
    int lr = lane & 15, q = lane >> 4, lk8 = q << 3;
    bool isRes = (col0 >= od);
    int nt = K >> 5;

    int aoff = (tid >> 2) * K + ((tid & 3) << 3);
    const u16* gb = Bt + (size_t)(col0 + (tid >> 2)) * K + ((tid & 3) << 3);

    auto stage = [&](int buf, int k0, int row0) {
        char* la = (char*)&lds[buf][0][0] + (wave << 10);
        char* lb = (char*)&lds[buf][1][0] + (wave << 10);
        const u16* ga = A + (size_t)row0 * K + aoff;
        gload16(ga + k0, la);
        gload16(ga + k0 + (size_t)64 * K, la + 4096);
        gload16(gb + k0, lb);
        gload16(gb + k0 + (size_t)64 * K, lb + 4096);
    };

    int buf = 0;
    stage(0, 0, by0 << 7);
    for (int ti = 0; ti < ntiles; ++ti) {
        int row0 = (by0 + ti) << 7;
        __syncthreads();   // first stage of this tile complete (drains prefetch)
        f32x4 acc[4][4];
#pragma unroll
        for (int mf = 0; mf < 4; ++mf)
#pragma unroll
            for (int nf = 0; nf < 4; ++nf) acc[mf][nf] = {0.f, 0.f, 0.f, 0.f};

        for (int t = 0; t < nt; ++t) {
            if (t + 1 < nt) stage(buf ^ 1, (t + 1) << 5, row0);
            const u16* La = (const u16*)lds[buf][0];
            const u16* Lb = (const u16*)lds[buf][1];
            s16x8 af[4], bfr[4];
#pragma unroll
            for (int mf = 0; mf < 4; ++mf) af[mf] = *(const s16x8*)(La + (wm + mf * 16 + lr) * 32 + lk8);
#pragma unroll
            for (int nf = 0; nf < 4; ++nf) bfr[nf] = *(const s16x8*)(Lb + (wn + nf * 16 + lr) * 32 + lk8);
#pragma unroll
            for (int mf = 0; mf < 4; ++mf)
#pragma unroll
                for (int nf = 0; nf < 4; ++nf)
                    acc[mf][nf] = __builtin_amdgcn_mfma_f32_16x16x32_bf16(bfr[nf], af[mf], acc[mf][nf], 0, 0, 0);
            if (t + 1 < nt) { __syncthreads(); buf ^= 1; }
        }
        // cross-tile prefetch: issue next tile's first stage NOW; epilogue hides its latency
        if (ti + 1 < ntiles) stage(buf ^ 1, 0, (by0 + ti + 1) << 7);

        // ---- C write: row = row0+wm+mf*16+lr ; col = col0+wn+nf*16+q*4 (+0..3 packed) ----
#pragma unroll
        for (int mf = 0; mf < 4; ++mf) {
            int row = row0 + wm + mf * 16 + lr;
            if (row < M) {
                if (isRes) {
#pragma unroll
                    for (int nf = 0; nf < 4; ++nf) {
                        int c = (col0 - od) + wn + nf * 16 + (q << 2);
                        float4 bv = *(const float4*)(res_b + c);
                        unsigned lo = (unsigned)f2b(acc[mf][nf][0] + bv.x) | ((unsigned)f2b(acc[mf][nf][1] + bv.y) << 16);
                        unsigned hi = (unsigned)f2b(acc[mf][nf][2] + bv.z) | ((unsigned)f2b(acc[mf][nf][3] + bv.w) << 16);
                        uint2 pk; pk.x = lo; pk.y = hi;
                        *(uint2*)(rr + (size_t)row * od + c) = pk;
                    }
                } else {
#pragma unroll
                    for (int nf = 0; nf < 4; ++nf) {
                        int c = col0 + wn + nf * 16 + (q << 2);
                        unsigned lo = (unsigned)f2b(acc[mf][nf][0]) | ((unsigned)f2b(acc[mf][nf][1]) << 16);
                        unsigned hi = (unsigned)f2b(acc[mf][nf][2]) | ((unsigned)f2b(acc[mf][nf][3]) << 16);
                        uint2 pk; pk.x = lo; pk.y = hi;
                        *(uint2*)(xl + (size_t)row * od + c) = pk;
                    }
                }
            }
        }
        // ---- fused scores for lin blocks (block covers one full head of 128 cols) ----
        if (!isRes) {
            int hh = (H == 4) ? (col0 >> 7) : 0;
            const float* asb = a_s + hh * 128 + wn + (q << 2);
            const float* adb = a_d + hh * 128 + wn + (q << 2);
            float4 as4[4], ad4[4];
#pragma unroll
            for (int nf = 0; nf < 4; ++nf) {
                as4[nf] = *(const float4*)(asb + nf * 16);
                ad4[nf] = *(const float4*)(adb + nf * 16);
            }
#pragma unroll
            for (int mf = 0; mf < 4; ++mf) {
                float vs = 0.f, vd = 0.f;
#pragma unroll
                for (int nf = 0; nf < 4; ++nf) {
                    vs += acc[mf][nf][0] * as4[nf].x + acc[mf][nf][1] * as4[nf].y
                        + acc[mf][nf][2] * as4[nf].z + acc[mf][nf][3] * as4[nf].w;
                    vd += acc[mf][nf][0] * ad4[nf].x + acc[mf][nf][1] * ad4[nf].y
                        + acc[mf][nf][2] * ad4[nf].z + acc[mf][nf][3] * ad4[nf].w;
                }
                vs += __shfl_xor(vs, 16); vs += __shfl_xor(vs, 32);
                vd += __shfl_xor(vd, 16); vd += __shfl_xor(vd, 32);
                if (q == 0) {
                    int rl = wm + mf * 16 + lr;
                    sred[wn >> 6][rl][0] = vs;
                    sred[wn >> 6][rl][1] = vd;
                }
            }
            __syncthreads();
            int rl = tid >> 1, which = tid & 1;
            int grow = row0 + rl;
            if (grow < M) {
                float v = sred[0][rl][which] + sred[1][rl][which];
                if (which == 0) ssrc[grow * H + hh] = v;
                else            sdst[grow * H + hh] = v;
            }
        }
        buf ^= 1;
    }
}

// ---------------- CSR build ----------------
__global__ void bsum_k(const int* __restrict__ cnt, int* __restrict__ bsum) {
    __shared__ int sd[256];
    int t = threadIdx.x, i = blockIdx.x * 256 + t;
    sd[t] = (i < N) ? cnt[i] : 0;
    __syncthreads();
    for (int off = 128; off; off >>= 1) { if (t < off) sd[t] += sd[t + off]; __syncthreads(); }
    if (t == 0) bsum[blockIdx.x] = sd[0];
}

// block 0: exclusive scan of per-block sums ; block 1: group counts via binary search
__global__ void scan2_k(const int* __restrict__ bsum, int* __restrict__ boff, int nb,
                        const int* __restrict__ batch, int* __restrict__ cntg) {
    if (blockIdx.x == 0) {
        __shared__ int sd[256];
        int t = threadIdx.x;
        int v = (t < nb) ? bsum[t] : 0;
        sd[t] = v;
        __syncthreads();
        for (int off = 1; off < 256; off <<= 1) {
            int tmp = (t >= off) ? sd[t - off] : 0;
            __syncthreads();
            sd[t] += tmp;
            __syncthreads();
        }
        if (t < nb) boff[t] = sd[t] - v;  // exclusive
    } else {
        int g = threadIdx.x;
        if (g >= G) return;
        int lo = 0, hi = N;
        while (lo < hi) { int mid = (lo + hi) >> 1; if (batch[mid] < g) lo = mid + 1; else hi = mid; }
        int lb0 = lo;
        lo = 0; hi = N;
        while (lo < hi) { int mid = (lo + hi) >> 1; if (batch[mid] < g + 1) lo = mid + 1; else hi = mid; }
        cntg[g] = lo - lb0;
    }
}

// per-block inclusive scan + block offset; writes indptr (inclusive at i+1) and fill (exclusive at i)
__global__ void iscan_k(const int* __restrict__ cnt, const int* __restrict__ boff,
                        int* __restrict__ indptr, int* __restrict__ fill) {
    __shared__ int sd[256];
    int b = blockIdx.x, t = threadIdx.x, i = b * 256 + t;
    int v = (i < N) ? cnt[i] : 0;
    sd[t] = v;
    __syncthreads();
    for (int off = 1; off < 256; off <<= 1) {
        int tmp = (t >= off) ? sd[t - off] : 0;
        __syncthreads();
        sd[t] += tmp;
        __syncthreads();
    }
    if (i < N) {
        int incl = boff[b] + sd[t];
        indptr[i + 1] = incl;
        fill[i] = incl - v;
    }
    if (i == 0) indptr[0] = 0;
}

__global__ void scatter_k(const int* __restrict__ ei, int* __restrict__ fill, int* __restrict__ out, int E, int ET) {
    int e = blockIdx.x * 256 + threadIdx.x;
    if (e >= ET) return;
    int s, d;
    if (e < E) { s = ei[e]; d = ei[E + e]; } else { s = d = e - E; }
    int pos = atomicAdd(&fill[d], 1);
    out[pos] = s;
}

// ---------------- GAT aggregation + bias/BN/relu + residual add (h_next in-place into rr) ----------------
template<int H, int OD>
__global__ __launch_bounds__(256) void agg_k(const u16* __restrict__ xl, const float* __restrict__ ssrc,
                                             const float* __restrict__ sdst, const int* __restrict__ indptr,
                                             const int* __restrict__ srcs, const float* __restrict__ bias,
                                             const float* __restrict__ bng, const float* __restrict__ bnb,
                                             const float* __restrict__ bnm, const float* __restrict__ bnv,
                                             u16* __restrict__ rr) {
    int w = (blockIdx.x * 256 + threadIdx.x) >> 6;
    int lane = threadIdx.x & 63;
    if (w >= N) return;
    int beg = indptr[w], deg = indptr[w + 1] - beg;
    constexpr int GRP = (H == 4) ? 16 : 64;
    int h = (H == 4) ? (lane >> 4) : 0;
    float sdl = sdst[w * H + h];
    float lmax = -3.4e38f, lsum = 0.f;
    int sub = lane & (GRP - 1);
    for (int e = sub; e < deg; e += GRP) {
        int s = srcs[beg + e];
        float v = ssrc[s * H + h] + sdl;
        v = v > 0.f ? v : 0.2f * v;
        lmax = fmaxf(lmax, v);
    }
#pragma unroll
    for (int o = GRP >> 1; o; o >>= 1) lmax = fmaxf(lmax, __shfl_xor(lmax, o));
    for (int e = sub; e < deg; e += GRP) {
        int s = srcs[beg + e];
        float v = ssrc[s * H + h] + sdl;
        v = v > 0.f ? v : 0.2f * v;
        lsum += __expf(v - lmax);
    }
#pragma unroll
    for (int o = GRP >> 1; o; o >>= 1) lsum += __shfl_xor(lsum, o);
    float inv = 1.0f / lsum;

    constexpr int EPL = OD / 64;
    float acc[EPL];
#pragma unroll
    for (int j = 0; j < EPL; ++j) acc[j] = 0.f;
    int e = 0;
    for (; e + 2 <= deg; e += 2) {
        int s0 = srcs[beg + e];
        int s1 = srcs[beg + e + 1];
        float v0 = ssrc[s0 * H + h] + sdl;
        float v1 = ssrc[s1 * H + h] + sdl;
        v0 = v0 > 0.f ? v0 : 0.2f * v0;
        v1 = v1 > 0.f ? v1 : 0.2f * v1;
        float wg0 = __expf(v0 - lmax) * inv;
        float wg1 = __expf(v1 - lmax) * inv;
        if constexpr (EPL == 8) {
            s16x8 xv0 = *(const s16x8*)(xl + (size_t)s0 * OD + lane * 8);
            s16x8 xv1 = *(const s16x8*)(xl + (size_t)s1 * OD + lane * 8);
#pragma unroll
            for (int j = 0; j < 8; ++j) acc[j] += b2f((u16)xv0[j]) * wg0;
#pragma unroll
            for (int j = 0; j < 8; ++j) acc[j] += b2f((u16)xv1[j]) * wg1;
        } else {
            unsigned xv0 = *(const unsigned*)(xl + (size_t)s0 * OD + lane * 2);
            unsigned xv1 = *(const unsigned*)(xl + (size_t)s1 * OD + lane * 2);
            acc[0] += b2f((u16)(xv0 & 0xffff)) * wg0;
            acc[1] += b2f((u16)(xv0 >> 16)) * wg0;
            acc[0] += b2f((u16)(xv1 & 0xffff)) * wg1;
            acc[1] += b2f((u16)(xv1 >> 16)) * wg1;
        }
    }
    for (; e < deg; ++e) {
        int s = srcs[beg + e];
        float v = ssrc[s * H + h] + sdl;
        v = v > 0.f ? v : 0.2f * v;
        float wg = __expf(v - lmax) * inv;
        if constexpr (EPL == 8) {
            s16x8 xv = *(const s16x8*)(xl + (size_t)s * OD + lane * 8);
#pragma unroll
            for (int j = 0; j < 8; ++j) acc[j] += b2f((u16)xv[j]) * wg;
        } else {
            unsigned xv = *(const unsigned*)(xl + (size_t)s * OD + lane * 2);
            acc[0] += b2f((u16)(xv & 0xffff)) * wg;
            acc[1] += b2f((u16)(xv >> 16)) * wg;
        }
    }
    if constexpr (EPL == 8) {
        s16x8 rv = *(const s16x8*)(rr + (size_t)w * OD + lane * 8);
        s16x8 ov;
#pragma unroll
        for (int j = 0; j < 8; ++j) {
            int c = lane * 8 + j;
            float v = acc[j] + bias[c] - bnm[c];
            v = v * rsqrtf(bnv[c] + 1e-5f) * bng[c] + bnb[c];
            ov[j] = (short)f2b(b2f((u16)rv[j]) + fmaxf(v, 0.f));
        }
        *(s16x8*)(rr + (size_t)w * OD + lane * 8) = ov;
    } else {
        unsigned rv = *(const unsigned*)(rr + (size_t)w * OD + lane * 2);
        unsigned o01 = 0;
#pragma unroll
        for (int j = 0; j < 2; ++j) {
            int c = lane * 2 + j;
            float v = acc[j] + bias[c] - bnm[c];
            v = v * rsqrtf(bnv[c] + 1e-5f) * bng[c] + bnb[c];
            float hv = b2f((u16)((rv >> (16 * j)) & 0xffff)) + fmaxf(v, 0.f);
            o01 |= ((unsigned)f2b(hv)) << (16 * j);
        }
        *(unsigned*)(rr + (size_t)w * OD + lane * 2) = o01;
    }
}

// ---------------- pooling ----------------
__device__ inline unsigned fkey(float f) {
    unsigned u = __float_as_uint(f);
    return (u & 0x80000000u) ? ~u : (u | 0x80000000u);
}

__global__ __launch_bounds__(128) void pool_k(const u16* __restrict__ h, const int* __restrict__ batch,
                                              float* __restrict__ psum, unsigned* __restrict__ pmax) {
    int c = threadIdx.x;
    int n0 = blockIdx.x * 64;
    if (n0 >= N) return;
    int nend = min(n0 + 64, N);
    int cur = batch[n0];
    float acc = 0.f, mx = -3.4e38f;
    for (int i = n0; i < nend; ++i) {
        int g = batch[i];
        if (g != cur) {
            atomicAdd(&psum[cur * 128 + c], acc);
            atomicMax(&pmax[cur * 128 + c], fkey(mx));
            acc = 0.f; mx = -3.4e38f; cur = g;
        }
        float v = b2f(h[(size_t)i * 128 + c]);
        acc += v;
        mx = fmaxf(mx, v);
    }
    atomicAdd(&psum[cur * 128 + c], acc);
    atomicMax(&pmax[cur * 128 + c], fkey(mx));
}

// ---------------- head: g=[mean,max] -> relu(g@W+b) -> LayerNorm (f32 out), 768 threads ----------------
__global__ __launch_bounds__(768) void head_k(const float* __restrict__ psum, const unsigned* __restrict__ pmax,
                                              const int* __restrict__ cntg, const float* __restrict__ W,
                                              const float* __restrict__ b, const float* __restrict__ lng,
                                              const float* __restrict__ lnb, float* __restrict__ out) {
    __shared__ float gin[256];
    __shared__ float red[768];
    int g = blockIdx.x, t = threadIdx.x;
    int cg = cntg[g];
    if (t < 256) {
        float val;
        if (t < 128) {
            val = psum[g * 128 + t] / fmaxf((float)cg, 1.0f);
        } else {
            unsigned k = pmax[g * 128 + (t - 128)];
            if (cg > 0 && k != 0u) {
                unsigned u = (k & 0x80000000u) ? (k ^ 0x80000000u) : ~k;
                val = __uint_as_float(u);
            } else val = 0.0f;
        }
        gin[t] = val;
    }
    __syncthreads();
    float s = b[t];
    for (int k = 0; k < 256; ++k) s += gin[k] * W[(size_t)k * OUT + t];
    float z = fmaxf(s, 0.f);
    red[t] = z;
    __syncthreads();
    if (t < 256) red[t] = red[t] + red[t + 256] + red[t + 512];
    __syncthreads();
    for (int off = 128; off; off >>= 1) { if (t < off) red[t] += red[t + off]; __syncthreads(); }
    float mu = red[0] / 768.0f;
    __syncthreads();
    float d = z - mu;
    red[t] = d * d;
    __syncthreads();
    if (t < 256) red[t] = red[t] + red[t + 256] + red[t + 512];
    __syncthreads();
    for (int off = 128; off; off >>= 1) { if (t < off) red[t] += red[t + off]; __syncthreads(); }
    float inv = rsqrtf(red[0] / 768.0f + 1e-5f);
    out[(size_t)g * OUT + t] = d * inv * lng[t] + lnb[t];
}

extern "C" void kernel_launch(void* const* d_in, const int* in_sizes, int n_in,
                              void* d_out, int out_size, void* d_ws, size_t ws_size,
                              hipStream_t stream) {
    const float* x = (const float*)d_in[0];
    const int* node_ids = (const int*)d_in[1];
    const int* ei = (const int*)d_in[2];
    const int* batch = (const int*)d_in[3];
    const float* emb = (const float*)d_in[4];
    const float* in_W = (const float*)d_in[5];
    const float* in_b = (const float*)d_in[6];
    const float* L[3][10];
    for (int l = 0; l < 3; ++l)
        for (int q = 0; q < 10; ++q) L[l][q] = (const float*)d_in[7 + l * 10 + q];
    const float* out_W = (const float*)d_in[37];
    const float* out_b = (const float*)d_in[38];
    const float* ln_g = (const float*)d_in[39];
    const float* ln_b = (const float*)d_in[40];
    int E = in_sizes[2] / 2;
    int ET = E + N;
    const int NBLK = (N + 255) / 256;   // 196

    char* ws = (char*)d_ws;
    size_t off = 0;
    auto alloc = [&](size_t bytes) -> void* {
        void* p = ws + off;
        off += (bytes + 255) & ~(size_t)255;
        return p;
    };
    const size_t NBH = (size_t)MPAD * 512 * sizeof(u16);
    u16* bufA = (u16*)alloc(NBH);
    u16* bufB = (u16*)alloc(NBH);
    u16* bufC = (u16*)alloc(NBH);
    const int lp[3] = {128, 512, 512};
    const int lod[3] = {512, 512, 128};
    u16* wcomb[3];
    for (int l = 0; l < 3; ++l) wcomb[l] = (u16*)alloc((size_t)2 * lod[l] * lp[l] * sizeof(u16));
    float* ssrc = (float*)alloc((size_t)N * 4 * sizeof(float));
    float* sdst = (float*)alloc((size_t)N * 4 * sizeof(float));
    int* cnt = (int*)alloc((size_t)N * sizeof(int));
    int* indptr = (int*)alloc((size_t)(N + 1) * sizeof(int));
    int* fill = (int*)alloc((size_t)N * sizeof(int));
    int* ssorted = (int*)alloc((size_t)ET * sizeof(int));
    int* bsum = (int*)alloc(256 * sizeof(int));
    int* boff = (int*)alloc(256 * sizeof(int));
    float* psum = (float*)alloc(G * 128 * sizeof(float));
    unsigned* pmax = (unsigned*)alloc(G * 128 * sizeof(unsigned));
    int* cntg = (int*)alloc(G * sizeof(int));

    if (off > ws_size) return;  // clean diagnostic failure instead of OOB fault

    hipMemsetAsync(cnt, 0, (size_t)N * sizeof(int), stream);
    hipMemsetAsync(psum, 0, G * 128 * sizeof(float), stream);
    hipMemsetAsync(pmax, 0, G * 128 * sizeof(unsigned), stream);

    // fused prep: input transform ∥ edge count ∥ weight cvt (3072 blocks of cvt)
    int nbCnt = (ET + 255) / 256;
    prep_k<<<25000 + nbCnt + 3072, 256, 0, stream>>>(x, node_ids, emb, in_W, in_b, bufA,
                                                     ei, cnt, E, ET, nbCnt,
                                                     L[0][0], L[0][8], wcomb[0],
                                                     L[1][0], L[1][8], wcomb[1],
                                                     L[2][0], L[2][8], wcomb[2]);
    bsum_k<<<NBLK, 256, 0, stream>>>(cnt, bsum);
    scan2_k<<<2, 256, 0, stream>>>(bsum, boff, NBLK, batch, cntg);
    iscan_k<<<NBLK, 256, 0, stream>>>(cnt, boff, indptr, fill);
    scatter_k<<<(ET + 255) / 256, 256, 0, stream>>>(ei, fill, ssorted, E, ET);

    u16* h = bufA;
    u16* xb = bufB;
    u16* rb = bufC;
    const int totTiles = (N + 127) >> 7;  // 391
    for (int l = 0; l < 3; ++l) {
        int p = lp[l], od = lod[l];
        int nbx = od >> 6;
        if (l == 0) {
            int grid = nbx * ((totTiles + 3) / 4);   // 8 * 98 = 784
            gemm2_k<0, 4, 4><<<grid, 256, 0, stream>>>(h, wcomb[l], L[l][9], L[l][1], L[l][2],
                                                       xb, rb, ssrc, sdst, N, od, p);
        } else if (l == 1) {
            int grid = nbx * ((totTiles + 3) / 4);   // 16 * 98 = 1568
            gemm2_k<1, 4, 4><<<grid, 256, 0, stream>>>(h, wcomb[l], L[l][9], L[l][1], L[l][2],
                                                       xb, rb, ssrc, sdst, N, od, p);
        } else {
            int grid = nbx * totTiles;               // 2 * 391 = 782
            gemm2_k<2, 1, 1><<<grid, 256, 0, stream>>>(h, wcomb[l], L[l][9], L[l][1], L[l][2],
                                                       xb, rb, ssrc, sdst, N, od, p);
        }
        int sblocks = ((size_t)N * 64 + 255) / 256;
        if (l < 2)
            agg_k<4, 512><<<sblocks, 256, 0, stream>>>(xb, ssrc, sdst, indptr, ssorted,
                                                       L[l][3], L[l][4], L[l][5], L[l][6], L[l][7], rb);
        else
            agg_k<1, 128><<<sblocks, 256, 0, stream>>>(xb, ssrc, sdst, indptr, ssorted,
                                                       L[l][3], L[l][4], L[l][5], L[l][6], L[l][7], rb);
        // h_next now lives in rb; rotate buffers
        u16* t2 = h; h = rb; rb = xb; xb = t2;
    }

    pool_k<<<(N + 63) / 64, 128, 0, stream>>>(h, batch, psum, pmax);
    head_k<<<G, 768, 0, stream>>>(psum, pmax, cntg, out_W, out_b, ln_g, ln_b, (float*)d_out);
}

// Round 14
// 818.024 us; speedup vs baseline: 1.1678x; 1.1678x over previous
//
#include <hip/hip_runtime.h>

constexpr int N = 50000;
constexpr int G = 64;
constexpr int HID = 128;
constexpr int OUT = 768;
constexpr int MPAD = 50048;  // 391*128: GEMM A-tile reads never leave the buffer

typedef unsigned short u16;
typedef short s16x8 __attribute__((ext_vector_type(8)));
typedef float f32x4 __attribute__((ext_vector_type(4)));

__device__ inline float b2f(u16 b) { return __uint_as_float(((unsigned)b) << 16); }
__device__ inline u16 f2b(float f) {
    unsigned u = __float_as_uint(f);
    u += 0x7fff + ((u >> 16) & 1);   // round-to-nearest-even
    return (u16)(u >> 16);
}

__device__ inline void gload16(const void* g, void* l) {
    __builtin_amdgcn_global_load_lds((const __attribute__((address_space(1))) void*)g,
                                     (__attribute__((address_space(3))) void*)l, 16, 0, 0);
}

// ---------------- fused prep: input-transform ∥ edge-count ∥ weight-convert (independent work) ----
__global__ void prep_k(const float* __restrict__ x, const int* __restrict__ ids,
                       const float* __restrict__ emb, const float* __restrict__ inW,
                       const float* __restrict__ inb, u16* __restrict__ h,
                       const int* __restrict__ ei, int* __restrict__ cnt, int E, int ET, int nbCnt,
                       const float* __restrict__ lin0, const float* __restrict__ res0, u16* __restrict__ w0,
                       const float* __restrict__ lin1, const float* __restrict__ res1, u16* __restrict__ w1,
                       const float* __restrict__ lin2, const float* __restrict__ res2, u16* __restrict__ w2) {
    int b = blockIdx.x, t = threadIdx.x;
    if (b < 25000) {
        int idx = b * 256 + t;           // < N*HID = 6.4M exactly
        int i = idx >> 7, j = idx & 127;
        float s = inb[j] + emb[(size_t)ids[i] * HID + j];
        const float* xr = x + (size_t)i * 16;
#pragma unroll
        for (int k = 0; k < 16; ++k) s += xr[k] * inW[k * HID + j];
        h[idx] = f2b(s);
    } else if (b < 25000 + nbCnt) {
        int e = (b - 25000) * 256 + t;
        if (e < ET) {
            int d = (e < E) ? ei[E + e] : (e - E);
            atomicAdd(&cnt[d], 1);
        }
    } else {
        int i = (b - 25000 - nbCnt) * 256 + t;
        const float* lin; const float* res; u16* dst; int p, od;
        if (i < 131072)      { lin = lin0; res = res0; dst = w0; p = 128; od = 512; }
        else if (i < 655360) { lin = lin1; res = res1; dst = w1; p = 512; od = 512; i -= 131072; }
        else if (i < 786432) { lin = lin2; res = res2; dst = w2; p = 512; od = 128; i -= 655360; }
        else return;
        int o = i / p, k = i - o * p;
        float v = (o < od) ? lin[(size_t)k * od + o] : res[(size_t)k * od + (o - od)];
        dst[i] = f2b(v);
    }
}

// ---------------- fused MFMA GEMM: [xl | rr] = A @ [linW | resW]^T, + per-head scores ----------------
// BM=128, BN=128 (of 2*od), BK=32, 4 waves, 4x4 frags (round-9/11 verified geometry, 820us).
// NEW (round 14): rule-21 LDS swizzle — global_load_lds dest stays LINEAR; the global SOURCE
// chunk is XOR-permuted ((t&3)^((t>>3)&3)) and the ds_read chunk applies the same XOR
// (q^((lr>>1)&3)). Kills the 8-way bank conflict of the 64B-row-stride tile (6.4M/dispatch
// measured round 13) -> 2-way = free (m136). Math bit-identical; placement only.
template<int LAYER, int H>
__global__ __launch_bounds__(256) void gemm2_k(const u16* __restrict__ A, const u16* __restrict__ Bt,
                                               const float* __restrict__ res_b,
                                               const float* __restrict__ a_s, const float* __restrict__ a_d,
                                               u16* __restrict__ xl, u16* __restrict__ rr,
                                               float* __restrict__ ssrc, float* __restrict__ sdst,
                                               int M, int od, int K) {
    __shared__ __align__(16) u16 lds[2][2][4096];  // [buf][A/B][128 rows * 32 k]
    int tid = threadIdx.x;
    int nbx = od >> 6;                 // (2*od)/128 col blocks
    // bijective XCD swizzle (m204)
    int nwg = gridDim.x;
    int qq = nwg >> 3, r8 = nwg & 7;
    int xcd = blockIdx.x & 7, ii = blockIdx.x >> 3;
    int swz = (xcd < r8 ? xcd * (qq + 1) : r8 * (qq + 1) + (xcd - r8) * qq) + ii;
    int bx = swz % nbx, by = swz / nbx;
    int row0 = by << 7, col0 = bx << 7;
    int wave = tid >> 6, lane = tid & 63;
    int wm = (wave & 1) << 6, wn = (wave >> 1) << 6;
    int lr = lane & 15, q = lane >> 4;
    // swizzled k-chunk for ds_read: chunk q XOR (lr>>1)&3  (constant per lane)
    int lk8 = ((q ^ ((lr >> 1) & 3)) << 3);

    // staging: LDS slot (row t>>2, chunk t&3) receives global chunk (t&3)^((t>>3)&3)
    int schunk = ((tid & 3) ^ ((tid >> 3) & 3)) << 3;
    const u16* ga = A + (size_t)(row0 + (tid >> 2)) * K + schunk;
    const u16* gb = Bt + (size_t)(col0 + (tid >> 2)) * K + schunk;

    f32x4 acc[4][4];
#pragma unroll
    for (int mf = 0; mf < 4; ++mf)
#pragma unroll
        for (int nf = 0; nf < 4; ++nf) acc[mf][nf] = {0.f, 0.f, 0.f, 0.f};

    auto stage = [&](int buf, int k0) {
        char* la = (char*)&lds[buf][0][0] + (wave << 10);
        char* lb = (char*)&lds[buf][1][0] + (wave << 10);
        gload16(ga + k0, la);
        gload16(ga + k0 + (size_t)64 * K, la + 4096);
        gload16(gb + k0, lb);
        gload16(gb + k0 + (size_t)64 * K, lb + 4096);
    };

    int nt = K >> 5;
    stage(0, 0);
    __syncthreads();
    int buf = 0;
    for (int t = 0; t < nt; ++t) {
        if (t + 1 < nt) stage(buf ^ 1, (t + 1) << 5);
        const u16* La = (const u16*)lds[buf][0];
        const u16* Lb = (const u16*)lds[buf][1];
        s16x8 af[4], bfr[4];
#pragma unroll
        for (int mf = 0; mf < 4; ++mf) af[mf] = *(const s16x8*)(La + (wm + mf * 16 + lr) * 32 + lk8);
#pragma unroll
        for (int nf = 0; nf < 4; ++nf) bfr[nf] = *(const s16x8*)(Lb + (wn + nf * 16 + lr) * 32 + lk8);
#pragma unroll
        for (int mf = 0; mf < 4; ++mf)
#pragma unroll
            for (int nf = 0; nf < 4; ++nf)
                acc[mf][nf] = __builtin_amdgcn_mfma_f32_16x16x32_bf16(bfr[nf], af[mf], acc[mf][nf], 0, 0, 0);
        __syncthreads();
        buf ^= 1;
    }

    bool isRes = (col0 >= od);
    // ---- C write: row = row0+wm+mf*16+lr ; col = col0+wn+nf*16+q*4 (+0..3 packed) ----
#pragma unroll
    for (int mf = 0; mf < 4; ++mf) {
        int row = row0 + wm + mf * 16 + lr;
        if (row < M) {
            if (isRes) {
#pragma unroll
                for (int nf = 0; nf < 4; ++nf) {
                    int c = (col0 - od) + wn + nf * 16 + (q << 2);
                    float4 bv = *(const float4*)(res_b + c);
                    unsigned lo = (unsigned)f2b(acc[mf][nf][0] + bv.x) | ((unsigned)f2b(acc[mf][nf][1] + bv.y) << 16);
                    unsigned hi = (unsigned)f2b(acc[mf][nf][2] + bv.z) | ((unsigned)f2b(acc[mf][nf][3] + bv.w) << 16);
                    uint2 pk; pk.x = lo; pk.y = hi;
                    *(uint2*)(rr + (size_t)row * od + c) = pk;
                }
            } else {
#pragma unroll
                for (int nf = 0; nf < 4; ++nf) {
                    int c = col0 + wn + nf * 16 + (q << 2);
                    unsigned lo = (unsigned)f2b(acc[mf][nf][0]) | ((unsigned)f2b(acc[mf][nf][1]) << 16);
                    unsigned hi = (unsigned)f2b(acc[mf][nf][2]) | ((unsigned)f2b(acc[mf][nf][3]) << 16);
                    uint2 pk; pk.x = lo; pk.y = hi;
                    *(uint2*)(xl + (size_t)row * od + c) = pk;
                }
            }
        }
    }
    // ---- fused scores for lin blocks (block covers one full head of 128 cols) ----
    if (!isRes) {
        int hh = (H == 4) ? (col0 >> 7) : 0;
        const float* asb = a_s + hh * 128 + wn + (q << 2);
        const float* adb = a_d + hh * 128 + wn + (q << 2);
        float4 as4[4], ad4[4];
#pragma unroll
        for (int nf = 0; nf < 4; ++nf) {
            as4[nf] = *(const float4*)(asb + nf * 16);
            ad4[nf] = *(const float4*)(adb + nf * 16);
        }
        float* sred = (float*)&lds[0][0][0];  // [2 wn-halves][128 rows][2] (K-loop done; sealed by barrier)
#pragma unroll
        for (int mf = 0; mf < 4; ++mf) {
            float vs = 0.f, vd = 0.f;
#pragma unroll
            for (int nf = 0; nf < 4; ++nf) {
                vs += acc[mf][nf][0] * as4[nf].x + acc[mf][nf][1] * as4[nf].y
                    + acc[mf][nf][2] * as4[nf].z + acc[mf][nf][3] * as4[nf].w;
                vd += acc[mf][nf][0] * ad4[nf].x + acc[mf][nf][1] * ad4[nf].y
                    + acc[mf][nf][2] * ad4[nf].z + acc[mf][nf][3] * ad4[nf].w;
            }
            vs += __shfl_xor(vs, 16); vs += __shfl_xor(vs, 32);
            vd += __shfl_xor(vd, 16); vd += __shfl_xor(vd, 32);
            if (q == 0) {
                int rl = wm + mf * 16 + lr;
                sred[(wn >> 6) * 256 + rl * 2 + 0] = vs;
                sred[(wn >> 6) * 256 + rl * 2 + 1] = vd;
            }
        }
        __syncthreads();
        int rl = tid >> 1, which = tid & 1;
        int grow = row0 + rl;
        if (grow < M) {
            float v = sred[rl * 2 + which] + sred[256 + rl * 2 + which];
            if (which == 0) ssrc[grow * H + hh] = v;
            else            sdst[grow * H + hh] = v;
        }
    }
}

// ---------------- CSR build ----------------
__global__ void bsum_k(const int* __restrict__ cnt, int* __restrict__ bsum) {
    __shared__ int sd[256];
    int t = threadIdx.x, i = blockIdx.x * 256 + t;
    sd[t] = (i < N) ? cnt[i] : 0;
    __syncthreads();
    for (int off = 128; off; off >>= 1) { if (t < off) sd[t] += sd[t + off]; __syncthreads(); }
    if (t == 0) bsum[blockIdx.x] = sd[0];
}

// block 0: exclusive scan of per-block sums ; block 1: group counts via binary search
__global__ void scan2_k(const int* __restrict__ bsum, int* __restrict__ boff, int nb,
                        const int* __restrict__ batch, int* __restrict__ cntg) {
    if (blockIdx.x == 0) {
        __shared__ int sd[256];
        int t = threadIdx.x;
        int v = (t < nb) ? bsum[t] : 0;
        sd[t] = v;
        __syncthreads();
        for (int off = 1; off < 256; off <<= 1) {
            int tmp = (t >= off) ? sd[t - off] : 0;
            __syncthreads();
            sd[t] += tmp;
            __syncthreads();
        }
        if (t < nb) boff[t] = sd[t] - v;  // exclusive
    } else {
        int g = threadIdx.x;
        if (g >= G) return;
        int lo = 0, hi = N;
        while (lo < hi) { int mid = (lo + hi) >> 1; if (batch[mid] < g) lo = mid + 1; else hi = mid; }
        int lb0 = lo;
        lo = 0; hi = N;
        while (lo < hi) { int mid = (lo + hi) >> 1; if (batch[mid] < g + 1) lo = mid + 1; else hi = mid; }
        cntg[g] = lo - lb0;
    }
}

// per-block inclusive scan + block offset; writes indptr (inclusive at i+1) and fill (exclusive at i)
__global__ void iscan_k(const int* __restrict__ cnt, const int* __restrict__ boff,
                        int* __restrict__ indptr, int* __restrict__ fill) {
    __shared__ int sd[256];
    int b = blockIdx.x, t = threadIdx.x, i = b * 256 + t;
    int v = (i < N) ? cnt[i] : 0;
    sd[t] = v;
    __syncthreads();
    for (int off = 1; off < 256; off <<= 1) {
        int tmp = (t >= off) ? sd[t - off] : 0;
        __syncthreads();
        sd[t] += tmp;
        __syncthreads();
    }
    if (i < N) {
        int incl = boff[b] + sd[t];
        indptr[i + 1] = incl;
        fill[i] = incl - v;
    }
    if (i == 0) indptr[0] = 0;
}

__global__ void scatter_k(const int* __restrict__ ei, int* __restrict__ fill, int* __restrict__ out, int E, int ET) {
    int e = blockIdx.x * 256 + threadIdx.x;
    if (e >= ET) return;
    int s, d;
    if (e < E) { s = ei[e]; d = ei[E + e]; } else { s = d = e - E; }
    int pos = atomicAdd(&fill[d], 1);
    out[pos] = s;
}

// ---------------- GAT aggregation + bias/BN/relu + residual add (h_next in-place into rr) ----------------
template<int H, int OD>
__global__ __launch_bounds__(256) void agg_k(const u16* __restrict__ xl, const float* __restrict__ ssrc,
                                             const float* __restrict__ sdst, const int* __restrict__ indptr,
                                             const int* __restrict__ srcs, const float* __restrict__ bias,
                                             const float* __restrict__ bng, const float* __restrict__ bnb,
                                             const float* __restrict__ bnm, const float* __restrict__ bnv,
                                             u16* __restrict__ rr) {
    int w = (blockIdx.x * 256 + threadIdx.x) >> 6;
    int lane = threadIdx.x & 63;
    if (w >= N) return;
    int beg = indptr[w], deg = indptr[w + 1] - beg;
    constexpr int GRP = (H == 4) ? 16 : 64;
    int h = (H == 4) ? (lane >> 4) : 0;
    float sdl = sdst[w * H + h];
    float lmax = -3.4e38f, lsum = 0.f;
    int sub = lane & (GRP - 1);
    for (int e = sub; e < deg; e += GRP) {
        int s = srcs[beg + e];
        float v = ssrc[s * H + h] + sdl;
        v = v > 0.f ? v : 0.2f * v;
        lmax = fmaxf(lmax, v);
    }
#pragma unroll
    for (int o = GRP >> 1; o; o >>= 1) lmax = fmaxf(lmax, __shfl_xor(lmax, o));
    for (int e = sub; e < deg; e += GRP) {
        int s = srcs[beg + e];
        float v = ssrc[s * H + h] + sdl;
        v = v > 0.f ? v : 0.2f * v;
        lsum += __expf(v - lmax);
    }
#pragma unroll
    for (int o = GRP >> 1; o; o >>= 1) lsum += __shfl_xor(lsum, o);
    float inv = 1.0f / lsum;

    constexpr int EPL = OD / 64;
    float acc[EPL];
#pragma unroll
    for (int j = 0; j < EPL; ++j) acc[j] = 0.f;
    int e = 0;
    for (; e + 2 <= deg; e += 2) {
        int s0 = srcs[beg + e];
        int s1 = srcs[beg + e + 1];
        float v0 = ssrc[s0 * H + h] + sdl;
        float v1 = ssrc[s1 * H + h] + sdl;
        v0 = v0 > 0.f ? v0 : 0.2f * v0;
        v1 = v1 > 0.f ? v1 : 0.2f * v1;
        float wg0 = __expf(v0 - lmax) * inv;
        float wg1 = __expf(v1 - lmax) * inv;
        if constexpr (EPL == 8) {
            s16x8 xv0 = *(const s16x8*)(xl + (size_t)s0 * OD + lane * 8);
            s16x8 xv1 = *(const s16x8*)(xl + (size_t)s1 * OD + lane * 8);
#pragma unroll
            for (int j = 0; j < 8; ++j) acc[j] += b2f((u16)xv0[j]) * wg0;
#pragma unroll
            for (int j = 0; j < 8; ++j) acc[j] += b2f((u16)xv1[j]) * wg1;
        } else {
            unsigned xv0 = *(const unsigned*)(xl + (size_t)s0 * OD + lane * 2);
            unsigned xv1 = *(const unsigned*)(xl + (size_t)s1 * OD + lane * 2);
            acc[0] += b2f((u16)(xv0 & 0xffff)) * wg0;
            acc[1] += b2f((u16)(xv0 >> 16)) * wg0;
            acc[0] += b2f((u16)(xv1 & 0xffff)) * wg1;
            acc[1] += b2f((u16)(xv1 >> 16)) * wg1;
        }
    }
    for (; e < deg; ++e) {
        int s = srcs[beg + e];
        float v = ssrc[s * H + h] + sdl;
        v = v > 0.f ? v : 0.2f * v;
        float wg = __expf(v - lmax) * inv;
        if constexpr (EPL == 8) {
            s16x8 xv = *(const s16x8*)(xl + (size_t)s * OD + lane * 8);
#pragma unroll
            for (int j = 0; j < 8; ++j) acc[j] += b2f((u16)xv[j]) * wg;
        } else {
            unsigned xv = *(const unsigned*)(xl + (size_t)s * OD + lane * 2);
            acc[0] += b2f((u16)(xv & 0xffff)) * wg;
            acc[1] += b2f((u16)(xv >> 16)) * wg;
        }
    }
    if constexpr (EPL == 8) {
        s16x8 rv = *(const s16x8*)(rr + (size_t)w * OD + lane * 8);
        s16x8 ov;
#pragma unroll
        for (int j = 0; j < 8; ++j) {
            int c = lane * 8 + j;
            float v = acc[j] + bias[c] - bnm[c];
            v = v * rsqrtf(bnv[c] + 1e-5f) * bng[c] + bnb[c];
            ov[j] = (short)f2b(b2f((u16)rv[j]) + fmaxf(v, 0.f));
        }
        *(s16x8*)(rr + (size_t)w * OD + lane * 8) = ov;
    } else {
        unsigned rv = *(const unsigned*)(rr + (size_t)w * OD + lane * 2);
        unsigned o01 = 0;
#pragma unroll
        for (int j = 0; j < 2; ++j) {
            int c = lane * 2 + j;
            float v = acc[j] + bias[c] - bnm[c];
            v = v * rsqrtf(bnv[c] + 1e-5f) * bng[c] + bnb[c];
            float hv = b2f((u16)((rv >> (16 * j)) & 0xffff)) + fmaxf(v, 0.f);
            o01 |= ((unsigned)f2b(hv)) << (16 * j);
        }
        *(unsigned*)(rr + (size_t)w * OD + lane * 2) = o01;
    }
}

// ---------------- pooling ----------------
__device__ inline unsigned fkey(float f) {
    unsigned u = __float_as_uint(f);
    return (u & 0x80000000u) ? ~u : (u | 0x80000000u);
}

__global__ __launch_bounds__(128) void pool_k(const u16* __restrict__ h, const int* __restrict__ batch,
                                              float* __restrict__ psum, unsigned* __restrict__ pmax) {
    int c = threadIdx.x;
    int n0 = blockIdx.x * 64;
    if (n0 >= N) return;
    int nend = min(n0 + 64, N);
    int cur = batch[n0];
    float acc = 0.f, mx = -3.4e38f;
    for (int i = n0; i < nend; ++i) {
        int g = batch[i];
        if (g != cur) {
            atomicAdd(&psum[cur * 128 + c], acc);
            atomicMax(&pmax[cur * 128 + c], fkey(mx));
            acc = 0.f; mx = -3.4e38f; cur = g;
        }
        float v = b2f(h[(size_t)i * 128 + c]);
        acc += v;
        mx = fmaxf(mx, v);
    }
    atomicAdd(&psum[cur * 128 + c], acc);
    atomicMax(&pmax[cur * 128 + c], fkey(mx));
}

// ---------------- head: g=[mean,max] -> relu(g@W+b) -> LayerNorm (f32 out), 768 threads ----------------
__global__ __launch_bounds__(768) void head_k(const float* __restrict__ psum, const unsigned* __restrict__ pmax,
                                              const int* __restrict__ cntg, const float* __restrict__ W,
                                              const float* __restrict__ b, const float* __restrict__ lng,
                                              const float* __restrict__ lnb, float* __restrict__ out) {
    __shared__ float gin[256];
    __shared__ float red[768];
    int g = blockIdx.x, t = threadIdx.x;
    int cg = cntg[g];
    if (t < 256) {
        float val;
        if (t < 128) {
            val = psum[g * 128 + t] / fmaxf((float)cg, 1.0f);
        } else {
            unsigned k = pmax[g * 128 + (t - 128)];
            if (cg > 0 && k != 0u) {
                unsigned u = (k & 0x80000000u) ? (k ^ 0x80000000u) : ~k;
                val = __uint_as_float(u);
            } else val = 0.0f;
        }
        gin[t] = val;
    }
    __syncthreads();
    float s = b[t];
    for (int k = 0; k < 256; ++k) s += gin[k] * W[(size_t)k * OUT + t];
    float z = fmaxf(s, 0.f);
    red[t] = z;
    __syncthreads();
    if (t < 256) red[t] = red[t] + red[t + 256] + red[t + 512];
    __syncthreads();
    for (int off = 128; off; off >>= 1) { if (t < off) red[t] += red[t + off]; __syncthreads(); }
    float mu = red[0] / 768.0f;
    __syncthreads();
    float d = z - mu;
    red[t] = d * d;
    __syncthreads();
    if (t < 256) red[t] = red[t] + red[t + 256] + red[t + 512];
    __syncthreads();
    for (int off = 128; off; off >>= 1) { if (t < off) red[t] += red[t + off]; __syncthreads(); }
    float inv = rsqrtf(red[0] / 768.0f + 1e-5f);
    out[(size_t)g * OUT + t] = d * inv * lng[t] + lnb[t];
}

extern "C" void kernel_launch(void* const* d_in, const int* in_sizes, int n_in,
                              void* d_out, int out_size, void* d_ws, size_t ws_size,
                              hipStream_t stream) {
    const float* x = (const float*)d_in[0];
    const int* node_ids = (const int*)d_in[1];
    const int* ei = (const int*)d_in[2];
    const int* batch = (const int*)d_in[3];
    const float* emb = (const float*)d_in[4];
    const float* in_W = (const float*)d_in[5];
    const float* in_b = (const float*)d_in[6];
    const float* L[3][10];
    for (int l = 0; l < 3; ++l)
        for (int q = 0; q < 10; ++q) L[l][q] = (const float*)d_in[7 + l * 10 + q];
    const float* out_W = (const float*)d_in[37];
    const float* out_b = (const float*)d_in[38];
    const float* ln_g = (const float*)d_in[39];
    const float* ln_b = (const float*)d_in[40];
    int E = in_sizes[2] / 2;
    int ET = E + N;
    const int NBLK = (N + 255) / 256;   // 196

    char* ws = (char*)d_ws;
    size_t off = 0;
    auto alloc = [&](size_t bytes) -> void* {
        void* p = ws + off;
        off += (bytes + 255) & ~(size_t)255;
        return p;
    };
    const size_t NBH = (size_t)MPAD * 512 * sizeof(u16);
    u16* bufA = (u16*)alloc(NBH);
    u16* bufB = (u16*)alloc(NBH);
    u16* bufC = (u16*)alloc(NBH);
    const int lp[3] = {128, 512, 512};
    const int lod[3] = {512, 512, 128};
    u16* wcomb[3];
    for (int l = 0; l < 3; ++l) wcomb[l] = (u16*)alloc((size_t)2 * lod[l] * lp[l] * sizeof(u16));
    float* ssrc = (float*)alloc((size_t)N * 4 * sizeof(float));
    float* sdst = (float*)alloc((size_t)N * 4 * sizeof(float));
    int* cnt = (int*)alloc((size_t)N * sizeof(int));
    int* indptr = (int*)alloc((size_t)(N + 1) * sizeof(int));
    int* fill = (int*)alloc((size_t)N * sizeof(int));
    int* ssorted = (int*)alloc((size_t)ET * sizeof(int));
    int* bsum = (int*)alloc(256 * sizeof(int));
    int* boff = (int*)alloc(256 * sizeof(int));
    float* psum = (float*)alloc(G * 128 * sizeof(float));
    unsigned* pmax = (unsigned*)alloc(G * 128 * sizeof(unsigned));
    int* cntg = (int*)alloc(G * sizeof(int));

    if (off > ws_size) return;  // clean diagnostic failure instead of OOB fault

    hipMemsetAsync(cnt, 0, (size_t)N * sizeof(int), stream);
    hipMemsetAsync(psum, 0, G * 128 * sizeof(float), stream);
    hipMemsetAsync(pmax, 0, G * 128 * sizeof(unsigned), stream);

    // fused prep: input transform ∥ edge count ∥ weight cvt (3072 blocks of cvt)
    int nbCnt = (ET + 255) / 256;
    prep_k<<<25000 + nbCnt + 3072, 256, 0, stream>>>(x, node_ids, emb, in_W, in_b, bufA,
                                                     ei, cnt, E, ET, nbCnt,
                                                     L[0][0], L[0][8], wcomb[0],
                                                     L[1][0], L[1][8], wcomb[1],
                                                     L[2][0], L[2][8], wcomb[2]);
    bsum_k<<<NBLK, 256, 0, stream>>>(cnt, bsum);
    scan2_k<<<2, 256, 0, stream>>>(bsum, boff, NBLK, batch, cntg);
    iscan_k<<<NBLK, 256, 0, stream>>>(cnt, boff, indptr, fill);
    scatter_k<<<(ET + 255) / 256, 256, 0, stream>>>(ei, fill, ssorted, E, ET);

    u16* h = bufA;
    u16* xb = bufB;
    u16* rb = bufC;
    const int nby = MPAD >> 7;  // 391
    for (int l = 0; l < 3; ++l) {
        int p = lp[l], od = lod[l];
        int nbx = od >> 6;
        int grid = nbx * nby;
        if (l == 0)
            gemm2_k<0, 4><<<grid, 256, 0, stream>>>(h, wcomb[l], L[l][9], L[l][1], L[l][2],
                                                    xb, rb, ssrc, sdst, N, od, p);
        else if (l == 1)
            gemm2_k<1, 4><<<grid, 256, 0, stream>>>(h, wcomb[l], L[l][9], L[l][1], L[l][2],
                                                    xb, rb, ssrc, sdst, N, od, p);
        else
            gemm2_k<2, 1><<<grid, 256, 0, stream>>>(h, wcomb[l], L[l][9], L[l][1], L[l][2],
                                                    xb, rb, ssrc, sdst, N, od, p);
        int sblocks = ((size_t)N * 64 + 255) / 256;
        if (l < 2)
            agg_k<4, 512><<<sblocks, 256, 0, stream>>>(xb, ssrc, sdst, indptr, ssorted,
                                                       L[l][3], L[l][4], L[l][5], L[l][6], L[l][7], rb);
        else
            agg_k<1, 128><<<sblocks, 256, 0, stream>>>(xb, ssrc, sdst, indptr, ssorted,
                                                       L[l][3], L[l][4], L[l][5], L[l][6], L[l][7], rb);
        // h_next now lives in rb; rotate buffers
        u16* t2 = h; h = rb; rb = xb; xb = t2;
    }

    pool_k<<<(N + 63) / 64, 128, 0, stream>>>(h, batch, psum, pmax);
    head_k<<<G, 768, 0, stream>>>(psum, pmax, cntg, out_W, out_b, ln_g, ln_b, (float*)d_out);
}

// Round 15
// 795.735 us; speedup vs baseline: 1.2005x; 1.0280x over previous
//
#include <hip/hip_runtime.h>

constexpr int N = 50000;
constexpr int G = 64;
constexpr int HID = 128;
constexpr int OUT = 768;
constexpr int MPAD = 50048;  // 391*128: GEMM A-tile reads never leave the buffer

typedef unsigned short u16;
typedef short s16x8 __attribute__((ext_vector_type(8)));
typedef float f32x4 __attribute__((ext_vector_type(4)));

__device__ inline float b2f(u16 b) { return __uint_as_float(((unsigned)b) << 16); }
__device__ inline u16 f2b(float f) {
    unsigned u = __float_as_uint(f);
    u += 0x7fff + ((u >> 16) & 1);   // round-to-nearest-even
    return (u16)(u >> 16);
}

__device__ inline void gload16(const void* g, void* l) {
    __builtin_amdgcn_global_load_lds((const __attribute__((address_space(1))) void*)g,
                                     (__attribute__((address_space(3))) void*)l, 16, 0, 0);
}

// ---------------- fused prep: input-transform ∥ edge-count ∥ weight-convert (independent work) ----
__global__ void prep_k(const float* __restrict__ x, const int* __restrict__ ids,
                       const float* __restrict__ emb, const float* __restrict__ inW,
                       const float* __restrict__ inb, u16* __restrict__ h,
                       const int* __restrict__ ei, int* __restrict__ cnt, int E, int ET, int nbCnt,
                       const float* __restrict__ lin0, const float* __restrict__ res0, u16* __restrict__ w0,
                       const float* __restrict__ lin1, const float* __restrict__ res1, u16* __restrict__ w1,
                       const float* __restrict__ lin2, const float* __restrict__ res2, u16* __restrict__ w2) {
    int b = blockIdx.x, t = threadIdx.x;
    if (b < 25000) {
        int idx = b * 256 + t;           // < N*HID = 6.4M exactly
        int i = idx >> 7, j = idx & 127;
        float s = inb[j] + emb[(size_t)ids[i] * HID + j];
        const float* xr = x + (size_t)i * 16;
#pragma unroll
        for (int k = 0; k < 16; ++k) s += xr[k] * inW[k * HID + j];
        h[idx] = f2b(s);
    } else if (b < 25000 + nbCnt) {
        int e = (b - 25000) * 256 + t;
        if (e < ET) {
            int d = (e < E) ? ei[E + e] : (e - E);
            atomicAdd(&cnt[d], 1);
        }
    } else {
        int i = (b - 25000 - nbCnt) * 256 + t;
        const float* lin; const float* res; u16* dst; int p, od;
        if (i < 131072)      { lin = lin0; res = res0; dst = w0; p = 128; od = 512; }
        else if (i < 655360) { lin = lin1; res = res1; dst = w1; p = 512; od = 512; i -= 131072; }
        else if (i < 786432) { lin = lin2; res = res2; dst = w2; p = 512; od = 128; i -= 655360; }
        else return;
        int o = i / p, k = i - o * p;
        float v = (o < od) ? lin[(size_t)k * od + o] : res[(size_t)k * od + (o - od)];
        dst[i] = f2b(v);
    }
}

// ---------------- fused MFMA GEMM: [xl | rr] = A @ [linW | resW]^T, + per-head scores ----------------
// BM=128, BN=128 (of 2*od), BK=32, 4 waves, 4x4 frags (round-9/11 verified geometry, 818-820us).
// rule-21 LDS swizzle (verified-neutral at 2-phase per T2 regime gate; kept, harmless).
template<int LAYER, int H>
__global__ __launch_bounds__(256) void gemm2_k(const u16* __restrict__ A, const u16* __restrict__ Bt,
                                               const float* __restrict__ res_b,
                                               const float* __restrict__ a_s, const float* __restrict__ a_d,
                                               u16* __restrict__ xl, u16* __restrict__ rr,
                                               float* __restrict__ ssrc, float* __restrict__ sdst,
                                               int M, int od, int K) {
    __shared__ __align__(16) u16 lds[2][2][4096];  // [buf][A/B][128 rows * 32 k]
    int tid = threadIdx.x;
    int nbx = od >> 6;                 // (2*od)/128 col blocks
    // bijective XCD swizzle (m204)
    int nwg = gridDim.x;
    int qq = nwg >> 3, r8 = nwg & 7;
    int xcd = blockIdx.x & 7, ii = blockIdx.x >> 3;
    int swz = (xcd < r8 ? xcd * (qq + 1) : r8 * (qq + 1) + (xcd - r8) * qq) + ii;
    int bx = swz % nbx, by = swz / nbx;
    int row0 = by << 7, col0 = bx << 7;
    int wave = tid >> 6, lane = tid & 63;
    int wm = (wave & 1) << 6, wn = (wave >> 1) << 6;
    int lr = lane & 15, q = lane >> 4;
    int lk8 = ((q ^ ((lr >> 1) & 3)) << 3);

    int schunk = ((tid & 3) ^ ((tid >> 3) & 3)) << 3;
    const u16* ga = A + (size_t)(row0 + (tid >> 2)) * K + schunk;
    const u16* gb = Bt + (size_t)(col0 + (tid >> 2)) * K + schunk;

    f32x4 acc[4][4];
#pragma unroll
    for (int mf = 0; mf < 4; ++mf)
#pragma unroll
        for (int nf = 0; nf < 4; ++nf) acc[mf][nf] = {0.f, 0.f, 0.f, 0.f};

    auto stage = [&](int buf, int k0) {
        char* la = (char*)&lds[buf][0][0] + (wave << 10);
        char* lb = (char*)&lds[buf][1][0] + (wave << 10);
        gload16(ga + k0, la);
        gload16(ga + k0 + (size_t)64 * K, la + 4096);
        gload16(gb + k0, lb);
        gload16(gb + k0 + (size_t)64 * K, lb + 4096);
    };

    int nt = K >> 5;
    stage(0, 0);
    __syncthreads();
    int buf = 0;
    for (int t = 0; t < nt; ++t) {
        if (t + 1 < nt) stage(buf ^ 1, (t + 1) << 5);
        const u16* La = (const u16*)lds[buf][0];
        const u16* Lb = (const u16*)lds[buf][1];
        s16x8 af[4], bfr[4];
#pragma unroll
        for (int mf = 0; mf < 4; ++mf) af[mf] = *(const s16x8*)(La + (wm + mf * 16 + lr) * 32 + lk8);
#pragma unroll
        for (int nf = 0; nf < 4; ++nf) bfr[nf] = *(const s16x8*)(Lb + (wn + nf * 16 + lr) * 32 + lk8);
#pragma unroll
        for (int mf = 0; mf < 4; ++mf)
#pragma unroll
            for (int nf = 0; nf < 4; ++nf)
                acc[mf][nf] = __builtin_amdgcn_mfma_f32_16x16x32_bf16(bfr[nf], af[mf], acc[mf][nf], 0, 0, 0);
        __syncthreads();
        buf ^= 1;
    }

    bool isRes = (col0 >= od);
    // ---- C write: row = row0+wm+mf*16+lr ; col = col0+wn+nf*16+q*4 (+0..3 packed) ----
#pragma unroll
    for (int mf = 0; mf < 4; ++mf) {
        int row = row0 + wm + mf * 16 + lr;
        if (row < M) {
            if (isRes) {
#pragma unroll
                for (int nf = 0; nf < 4; ++nf) {
                    int c = (col0 - od) + wn + nf * 16 + (q << 2);
                    float4 bv = *(const float4*)(res_b + c);
                    unsigned lo = (unsigned)f2b(acc[mf][nf][0] + bv.x) | ((unsigned)f2b(acc[mf][nf][1] + bv.y) << 16);
                    unsigned hi = (unsigned)f2b(acc[mf][nf][2] + bv.z) | ((unsigned)f2b(acc[mf][nf][3] + bv.w) << 16);
                    uint2 pk; pk.x = lo; pk.y = hi;
                    *(uint2*)(rr + (size_t)row * od + c) = pk;
                }
            } else {
#pragma unroll
                for (int nf = 0; nf < 4; ++nf) {
                    int c = col0 + wn + nf * 16 + (q << 2);
                    unsigned lo = (unsigned)f2b(acc[mf][nf][0]) | ((unsigned)f2b(acc[mf][nf][1]) << 16);
                    unsigned hi = (unsigned)f2b(acc[mf][nf][2]) | ((unsigned)f2b(acc[mf][nf][3]) << 16);
                    uint2 pk; pk.x = lo; pk.y = hi;
                    *(uint2*)(xl + (size_t)row * od + c) = pk;
                }
            }
        }
    }
    // ---- fused scores for lin blocks (block covers one full head of 128 cols) ----
    if (!isRes) {
        int hh = (H == 4) ? (col0 >> 7) : 0;
        const float* asb = a_s + hh * 128 + wn + (q << 2);
        const float* adb = a_d + hh * 128 + wn + (q << 2);
        float4 as4[4], ad4[4];
#pragma unroll
        for (int nf = 0; nf < 4; ++nf) {
            as4[nf] = *(const float4*)(asb + nf * 16);
            ad4[nf] = *(const float4*)(adb + nf * 16);
        }
        float* sred = (float*)&lds[0][0][0];  // K-loop done; sealed by barrier
#pragma unroll
        for (int mf = 0; mf < 4; ++mf) {
            float vs = 0.f, vd = 0.f;
#pragma unroll
            for (int nf = 0; nf < 4; ++nf) {
                vs += acc[mf][nf][0] * as4[nf].x + acc[mf][nf][1] * as4[nf].y
                    + acc[mf][nf][2] * as4[nf].z + acc[mf][nf][3] * as4[nf].w;
                vd += acc[mf][nf][0] * ad4[nf].x + acc[mf][nf][1] * ad4[nf].y
                    + acc[mf][nf][2] * ad4[nf].z + acc[mf][nf][3] * ad4[nf].w;
            }
            vs += __shfl_xor(vs, 16); vs += __shfl_xor(vs, 32);
            vd += __shfl_xor(vd, 16); vd += __shfl_xor(vd, 32);
            if (q == 0) {
                int rl = wm + mf * 16 + lr;
                sred[(wn >> 6) * 256 + rl * 2 + 0] = vs;
                sred[(wn >> 6) * 256 + rl * 2 + 1] = vd;
            }
        }
        __syncthreads();
        int rl = tid >> 1, which = tid & 1;
        int grow = row0 + rl;
        if (grow < M) {
            float v = sred[rl * 2 + which] + sred[256 + rl * 2 + which];
            if (which == 0) ssrc[grow * H + hh] = v;
            else            sdst[grow * H + hh] = v;
        }
    }
}

// ---------------- CSR build ----------------
__global__ void bsum_k(const int* __restrict__ cnt, int* __restrict__ bsum) {
    __shared__ int sd[256];
    int t = threadIdx.x, i = blockIdx.x * 256 + t;
    sd[t] = (i < N) ? cnt[i] : 0;
    __syncthreads();
    for (int off = 128; off; off >>= 1) { if (t < off) sd[t] += sd[t + off]; __syncthreads(); }
    if (t == 0) bsum[blockIdx.x] = sd[0];
}

// block 0: exclusive scan of per-block sums ; block 1: group counts via binary search
__global__ void scan2_k(const int* __restrict__ bsum, int* __restrict__ boff, int nb,
                        const int* __restrict__ batch, int* __restrict__ cntg) {
    if (blockIdx.x == 0) {
        __shared__ int sd[256];
        int t = threadIdx.x;
        int v = (t < nb) ? bsum[t] : 0;
        sd[t] = v;
        __syncthreads();
        for (int off = 1; off < 256; off <<= 1) {
            int tmp = (t >= off) ? sd[t - off] : 0;
            __syncthreads();
            sd[t] += tmp;
            __syncthreads();
        }
        if (t < nb) boff[t] = sd[t] - v;  // exclusive
    } else {
        int g = threadIdx.x;
        if (g >= G) return;
        int lo = 0, hi = N;
        while (lo < hi) { int mid = (lo + hi) >> 1; if (batch[mid] < g) lo = mid + 1; else hi = mid; }
        int lb0 = lo;
        lo = 0; hi = N;
        while (lo < hi) { int mid = (lo + hi) >> 1; if (batch[mid] < g + 1) lo = mid + 1; else hi = mid; }
        cntg[g] = lo - lb0;
    }
}

// per-block inclusive scan + block offset; writes indptr (inclusive at i+1) and fill (exclusive at i)
__global__ void iscan_k(const int* __restrict__ cnt, const int* __restrict__ boff,
                        int* __restrict__ indptr, int* __restrict__ fill) {
    __shared__ int sd[256];
    int b = blockIdx.x, t = threadIdx.x, i = b * 256 + t;
    int v = (i < N) ? cnt[i] : 0;
    sd[t] = v;
    __syncthreads();
    for (int off = 1; off < 256; off <<= 1) {
        int tmp = (t >= off) ? sd[t - off] : 0;
        __syncthreads();
        sd[t] += tmp;
        __syncthreads();
    }
    if (i < N) {
        int incl = boff[b] + sd[t];
        indptr[i + 1] = incl;
        fill[i] = incl - v;
    }
    if (i == 0) indptr[0] = 0;
}

__global__ void scatter_k(const int* __restrict__ ei, int* __restrict__ fill, int* __restrict__ out, int E, int ET) {
    int e = blockIdx.x * 256 + threadIdx.x;
    if (e >= ET) return;
    int s, d;
    if (e < E) { s = ei[e]; d = ei[E + e]; } else { s = d = e - E; }
    int pos = atomicAdd(&fill[d], 1);
    out[pos] = s;
}

// ---------------- GAT aggregation + bias/BN/relu + residual add (h_next in-place into rr) ----------------
// Round 15: online-softmax merges the max-pass and denom-pass into ONE gather pass;
// pass-3 row-gather unrolled x4 (4 independent 1KB gathers in flight).
template<int H, int OD>
__global__ __launch_bounds__(256) void agg_k(const u16* __restrict__ xl, const float* __restrict__ ssrc,
                                             const float* __restrict__ sdst, const int* __restrict__ indptr,
                                             const int* __restrict__ srcs, const float* __restrict__ bias,
                                             const float* __restrict__ bng, const float* __restrict__ bnb,
                                             const float* __restrict__ bnm, const float* __restrict__ bnv,
                                             u16* __restrict__ rr) {
    int w = (blockIdx.x * 256 + threadIdx.x) >> 6;
    int lane = threadIdx.x & 63;
    if (w >= N) return;
    int beg = indptr[w], deg = indptr[w + 1] - beg;
    constexpr int GRP = (H == 4) ? 16 : 64;
    int h = (H == 4) ? (lane >> 4) : 0;
    float sdl = sdst[w * H + h];
    // ---- single-pass online softmax (max + denom together) ----
    float lmax = -3.4e38f, lsum = 0.f;
    int sub = lane & (GRP - 1);
    for (int e = sub; e < deg; e += GRP) {
        int s = srcs[beg + e];
        float v = ssrc[s * H + h] + sdl;
        v = v > 0.f ? v : 0.2f * v;
        if (v > lmax) {
            lsum = lsum * __expf(lmax - v) + 1.0f;
            lmax = v;
        } else {
            lsum += __expf(v - lmax);
        }
    }
#pragma unroll
    for (int o = GRP >> 1; o; o >>= 1) {
        float mo = __shfl_xor(lmax, o);
        float so = __shfl_xor(lsum, o);
        float mn = fmaxf(lmax, mo);
        lsum = lsum * __expf(lmax - mn) + so * __expf(mo - mn);
        lmax = mn;
    }
    float inv = 1.0f / lsum;

    constexpr int EPL = OD / 64;
    float acc[EPL];
#pragma unroll
    for (int j = 0; j < EPL; ++j) acc[j] = 0.f;
    int e = 0;
    // ---- pass 3: weighted row-gather, unrolled x4 ----
    for (; e + 4 <= deg; e += 4) {
        int s0 = srcs[beg + e], s1 = srcs[beg + e + 1];
        int s2 = srcs[beg + e + 2], s3 = srcs[beg + e + 3];
        float v0 = ssrc[s0 * H + h] + sdl;
        float v1 = ssrc[s1 * H + h] + sdl;
        float v2 = ssrc[s2 * H + h] + sdl;
        float v3 = ssrc[s3 * H + h] + sdl;
        v0 = v0 > 0.f ? v0 : 0.2f * v0;
        v1 = v1 > 0.f ? v1 : 0.2f * v1;
        v2 = v2 > 0.f ? v2 : 0.2f * v2;
        v3 = v3 > 0.f ? v3 : 0.2f * v3;
        float wg0 = __expf(v0 - lmax) * inv;
        float wg1 = __expf(v1 - lmax) * inv;
        float wg2 = __expf(v2 - lmax) * inv;
        float wg3 = __expf(v3 - lmax) * inv;
        if constexpr (EPL == 8) {
            s16x8 xv0 = *(const s16x8*)(xl + (size_t)s0 * OD + lane * 8);
            s16x8 xv1 = *(const s16x8*)(xl + (size_t)s1 * OD + lane * 8);
            s16x8 xv2 = *(const s16x8*)(xl + (size_t)s2 * OD + lane * 8);
            s16x8 xv3 = *(const s16x8*)(xl + (size_t)s3 * OD + lane * 8);
#pragma unroll
            for (int j = 0; j < 8; ++j) acc[j] += b2f((u16)xv0[j]) * wg0;
#pragma unroll
            for (int j = 0; j < 8; ++j) acc[j] += b2f((u16)xv1[j]) * wg1;
#pragma unroll
            for (int j = 0; j < 8; ++j) acc[j] += b2f((u16)xv2[j]) * wg2;
#pragma unroll
            for (int j = 0; j < 8; ++j) acc[j] += b2f((u16)xv3[j]) * wg3;
        } else {
            unsigned xv0 = *(const unsigned*)(xl + (size_t)s0 * OD + lane * 2);
            unsigned xv1 = *(const unsigned*)(xl + (size_t)s1 * OD + lane * 2);
            unsigned xv2 = *(const unsigned*)(xl + (size_t)s2 * OD + lane * 2);
            unsigned xv3 = *(const unsigned*)(xl + (size_t)s3 * OD + lane * 2);
            acc[0] += b2f((u16)(xv0 & 0xffff)) * wg0 + b2f((u16)(xv1 & 0xffff)) * wg1
                    + b2f((u16)(xv2 & 0xffff)) * wg2 + b2f((u16)(xv3 & 0xffff)) * wg3;
            acc[1] += b2f((u16)(xv0 >> 16)) * wg0 + b2f((u16)(xv1 >> 16)) * wg1
                    + b2f((u16)(xv2 >> 16)) * wg2 + b2f((u16)(xv3 >> 16)) * wg3;
        }
    }
    for (; e < deg; ++e) {
        int s = srcs[beg + e];
        float v = ssrc[s * H + h] + sdl;
        v = v > 0.f ? v : 0.2f * v;
        float wg = __expf(v - lmax) * inv;
        if constexpr (EPL == 8) {
            s16x8 xv = *(const s16x8*)(xl + (size_t)s * OD + lane * 8);
#pragma unroll
            for (int j = 0; j < 8; ++j) acc[j] += b2f((u16)xv[j]) * wg;
        } else {
            unsigned xv = *(const unsigned*)(xl + (size_t)s * OD + lane * 2);
            acc[0] += b2f((u16)(xv & 0xffff)) * wg;
            acc[1] += b2f((u16)(xv >> 16)) * wg;
        }
    }
    if constexpr (EPL == 8) {
        s16x8 rv = *(const s16x8*)(rr + (size_t)w * OD + lane * 8);
        s16x8 ov;
#pragma unroll
        for (int j = 0; j < 8; ++j) {
            int c = lane * 8 + j;
            float v = acc[j] + bias[c] - bnm[c];
            v = v * rsqrtf(bnv[c] + 1e-5f) * bng[c] + bnb[c];
            ov[j] = (short)f2b(b2f((u16)rv[j]) + fmaxf(v, 0.f));
        }
        *(s16x8*)(rr + (size_t)w * OD + lane * 8) = ov;
    } else {
        unsigned rv = *(const unsigned*)(rr + (size_t)w * OD + lane * 2);
        unsigned o01 = 0;
#pragma unroll
        for (int j = 0; j < 2; ++j) {
            int c = lane * 2 + j;
            float v = acc[j] + bias[c] - bnm[c];
            v = v * rsqrtf(bnv[c] + 1e-5f) * bng[c] + bnb[c];
            float hv = b2f((u16)((rv >> (16 * j)) & 0xffff)) + fmaxf(v, 0.f);
            o01 |= ((unsigned)f2b(hv)) << (16 * j);
        }
        *(unsigned*)(rr + (size_t)w * OD + lane * 2) = o01;
    }
}

// ---------------- pooling ----------------
__device__ inline unsigned fkey(float f) {
    unsigned u = __float_as_uint(f);
    return (u & 0x80000000u) ? ~u : (u | 0x80000000u);
}

__global__ __launch_bounds__(128) void pool_k(const u16* __restrict__ h, const int* __restrict__ batch,
                                              float* __restrict__ psum, unsigned* __restrict__ pmax) {
    int c = threadIdx.x;
    int n0 = blockIdx.x * 64;
    if (n0 >= N) return;
    int nend = min(n0 + 64, N);
    int cur = batch[n0];
    float acc = 0.f, mx = -3.4e38f;
    for (int i = n0; i < nend; ++i) {
        int g = batch[i];
        if (g != cur) {
            atomicAdd(&psum[cur * 128 + c], acc);
            atomicMax(&pmax[cur * 128 + c], fkey(mx));
            acc = 0.f; mx = -3.4e38f; cur = g;
        }
        float v = b2f(h[(size_t)i * 128 + c]);
        acc += v;
        mx = fmaxf(mx, v);
    }
    atomicAdd(&psum[cur * 128 + c], acc);
    atomicMax(&pmax[cur * 128 + c], fkey(mx));
}

// ---------------- head: g=[mean,max] -> relu(g@W+b) -> LayerNorm (f32 out), 768 threads ----------------
__global__ __launch_bounds__(768) void head_k(const float* __restrict__ psum, const unsigned* __restrict__ pmax,
                                              const int* __restrict__ cntg, const float* __restrict__ W,
                                              const float* __restrict__ b, const float* __restrict__ lng,
                                              const float* __restrict__ lnb, float* __restrict__ out) {
    __shared__ float gin[256];
    __shared__ float red[768];
    int g = blockIdx.x, t = threadIdx.x;
    int cg = cntg[g];
    if (t < 256) {
        float val;
        if (t < 128) {
            val = psum[g * 128 + t] / fmaxf((float)cg, 1.0f);
        } else {
            unsigned k = pmax[g * 128 + (t - 128)];
            if (cg > 0 && k != 0u) {
                unsigned u = (k & 0x80000000u) ? (k ^ 0x80000000u) : ~k;
                val = __uint_as_float(u);
            } else val = 0.0f;
        }
        gin[t] = val;
    }
    __syncthreads();
    float s = b[t];
    for (int k = 0; k < 256; ++k) s += gin[k] * W[(size_t)k * OUT + t];
    float z = fmaxf(s, 0.f);
    red[t] = z;
    __syncthreads();
    if (t < 256) red[t] = red[t] + red[t + 256] + red[t + 512];
    __syncthreads();
    for (int off = 128; off; off >>= 1) { if (t < off) red[t] += red[t + off]; __syncthreads(); }
    float mu = red[0] / 768.0f;
    __syncthreads();
    float d = z - mu;
    red[t] = d * d;
    __syncthreads();
    if (t < 256) red[t] = red[t] + red[t + 256] + red[t + 512];
    __syncthreads();
    for (int off = 128; off; off >>= 1) { if (t < off) red[t] += red[t + off]; __syncthreads(); }
    float inv = rsqrtf(red[0] / 768.0f + 1e-5f);
    out[(size_t)g * OUT + t] = d * inv * lng[t] + lnb[t];
}

extern "C" void kernel_launch(void* const* d_in, const int* in_sizes, int n_in,
                              void* d_out, int out_size, void* d_ws, size_t ws_size,
                              hipStream_t stream) {
    const float* x = (const float*)d_in[0];
    const int* node_ids = (const int*)d_in[1];
    const int* ei = (const int*)d_in[2];
    const int* batch = (const int*)d_in[3];
    const float* emb = (const float*)d_in[4];
    const float* in_W = (const float*)d_in[5];
    const float* in_b = (const float*)d_in[6];
    const float* L[3][10];
    for (int l = 0; l < 3; ++l)
        for (int q = 0; q < 10; ++q) L[l][q] = (const float*)d_in[7 + l * 10 + q];
    const float* out_W = (const float*)d_in[37];
    const float* out_b = (const float*)d_in[38];
    const float* ln_g = (const float*)d_in[39];
    const float* ln_b = (const float*)d_in[40];
    int E = in_sizes[2] / 2;
    int ET = E + N;
    const int NBLK = (N + 255) / 256;   // 196

    char* ws = (char*)d_ws;
    size_t off = 0;
    auto alloc = [&](size_t bytes) -> void* {
        void* p = ws + off;
        off += (bytes + 255) & ~(size_t)255;
        return p;
    };
    const size_t NBH = (size_t)MPAD * 512 * sizeof(u16);
    u16* bufA = (u16*)alloc(NBH);
    u16* bufB = (u16*)alloc(NBH);
    u16* bufC = (u16*)alloc(NBH);
    const int lp[3] = {128, 512, 512};
    const int lod[3] = {512, 512, 128};
    u16* wcomb[3];
    for (int l = 0; l < 3; ++l) wcomb[l] = (u16*)alloc((size_t)2 * lod[l] * lp[l] * sizeof(u16));
    float* ssrc = (float*)alloc((size_t)N * 4 * sizeof(float));
    float* sdst = (float*)alloc((size_t)N * 4 * sizeof(float));
    int* cnt = (int*)alloc((size_t)N * sizeof(int));
    int* indptr = (int*)alloc((size_t)(N + 1) * sizeof(int));
    int* fill = (int*)alloc((size_t)N * sizeof(int));
    int* ssorted = (int*)alloc((size_t)ET * sizeof(int));
    int* bsum = (int*)alloc(256 * sizeof(int));
    int* boff = (int*)alloc(256 * sizeof(int));
    float* psum = (float*)alloc(G * 128 * sizeof(float));
    unsigned* pmax = (unsigned*)alloc(G * 128 * sizeof(unsigned));
    int* cntg = (int*)alloc(G * sizeof(int));

    if (off > ws_size) return;  // clean diagnostic failure instead of OOB fault

    hipMemsetAsync(cnt, 0, (size_t)N * sizeof(int), stream);
    hipMemsetAsync(psum, 0, G * 128 * sizeof(float), stream);
    hipMemsetAsync(pmax, 0, G * 128 * sizeof(unsigned), stream);

    // fused prep: input transform ∥ edge count ∥ weight cvt (3072 blocks of cvt)
    int nbCnt = (ET + 255) / 256;
    prep_k<<<25000 + nbCnt + 3072, 256, 0, stream>>>(x, node_ids, emb, in_W, in_b, bufA,
                                                     ei, cnt, E, ET, nbCnt,
                                                     L[0][0], L[0][8], wcomb[0],
                                                     L[1][0], L[1][8], wcomb[1],
                                                     L[2][0], L[2][8], wcomb[2]);
    bsum_k<<<NBLK, 256, 0, stream>>>(cnt, bsum);
    scan2_k<<<2, 256, 0, stream>>>(bsum, boff, NBLK, batch, cntg);
    iscan_k<<<NBLK, 256, 0, stream>>>(cnt, boff, indptr, fill);
    scatter_k<<<(ET + 255) / 256, 256, 0, stream>>>(ei, fill, ssorted, E, ET);

    u16* h = bufA;
    u16* xb = bufB;
    u16* rb = bufC;
    const int nby = MPAD >> 7;  // 391
    for (int l = 0; l < 3; ++l) {
        int p = lp[l], od = lod[l];
        int nbx = od >> 6;
        int grid = nbx * nby;
        if (l == 0)
            gemm2_k<0, 4><<<grid, 256, 0, stream>>>(h, wcomb[l], L[l][9], L[l][1], L[l][2],
                                                    xb, rb, ssrc, sdst, N, od, p);
        else if (l == 1)
            gemm2_k<1, 4><<<grid, 256, 0, stream>>>(h, wcomb[l], L[l][9], L[l][1], L[l][2],
                                                    xb, rb, ssrc, sdst, N, od, p);
        else
            gemm2_k<2, 1><<<grid, 256, 0, stream>>>(h, wcomb[l], L[l][9], L[l][1], L[l][2],
                                                    xb, rb, ssrc, sdst, N, od, p);
        int sblocks = ((size_t)N * 64 + 255) / 256;
        if (l < 2)
            agg_k<4, 512><<<sblocks, 256, 0, stream>>>(xb, ssrc, sdst, indptr, ssorted,
                                                       L[l][3], L[l][4], L[l][5], L[l][6], L[l][7], rb);
        else
            agg_k<1, 128><<<sblocks, 256, 0, stream>>>(xb, ssrc, sdst, indptr, ssorted,
                                                       L[l][3], L[l][4], L[l][5], L[l][6], L[l][7], rb);
        // h_next now lives in rb; rotate buffers
        u16* t2 = h; h = rb; rb = xb; xb = t2;
    }

    pool_k<<<(N + 63) / 64, 128, 0, stream>>>(h, batch, psum, pmax);
    head_k<<<G, 768, 0, stream>>>(psum, pmax, cntg, out_W, out_b, ln_g, ln_b, (float*)d_out);
}

// Round 16
// 780.752 us; speedup vs baseline: 1.2235x; 1.0192x over previous
//
#include <hip/hip_runtime.h>

constexpr int N = 50000;
constexpr int G = 64;
constexpr int HID = 128;
constexpr int OUT = 768;
constexpr int MPAD = 50048;  // 391*128: GEMM A-tile reads never leave the buffer

typedef unsigned short u16;
typedef short s16x8 __attribute__((ext_vector_type(8)));
typedef float f32x4 __attribute__((ext_vector_type(4)));

__device__ inline float b2f(u16 b) { return __uint_as_float(((unsigned)b) << 16); }
__device__ inline u16 f2b(float f) {
    unsigned u = __float_as_uint(f);
    u += 0x7fff + ((u >> 16) & 1);   // round-to-nearest-even
    return (u16)(u >> 16);
}

__device__ inline void gload16(const void* g, void* l) {
    __builtin_amdgcn_global_load_lds((const __attribute__((address_space(1))) void*)g,
                                     (__attribute__((address_space(3))) void*)l, 16, 0, 0);
}

// ---------------- fused prep: input-transform ∥ edge-count ∥ weight-convert (independent work) ----
__global__ void prep_k(const float* __restrict__ x, const int* __restrict__ ids,
                       const float* __restrict__ emb, const float* __restrict__ inW,
                       const float* __restrict__ inb, u16* __restrict__ h,
                       const int* __restrict__ ei, int* __restrict__ cnt, int E, int ET, int nbCnt,
                       const float* __restrict__ lin0, const float* __restrict__ res0, u16* __restrict__ w0,
                       const float* __restrict__ lin1, const float* __restrict__ res1, u16* __restrict__ w1,
                       const float* __restrict__ lin2, const float* __restrict__ res2, u16* __restrict__ w2) {
    int b = blockIdx.x, t = threadIdx.x;
    if (b < 25000) {
        int idx = b * 256 + t;           // < N*HID = 6.4M exactly
        int i = idx >> 7, j = idx & 127;
        float s = inb[j] + emb[(size_t)ids[i] * HID + j];
        const float* xr = x + (size_t)i * 16;
#pragma unroll
        for (int k = 0; k < 16; ++k) s += xr[k] * inW[k * HID + j];
        h[idx] = f2b(s);
    } else if (b < 25000 + nbCnt) {
        int e = (b - 25000) * 256 + t;
        if (e < ET) {
            int d = (e < E) ? ei[E + e] : (e - E);
            atomicAdd(&cnt[d], 1);
        }
    } else {
        int i = (b - 25000 - nbCnt) * 256 + t;
        const float* lin; const float* res; u16* dst; int p, od;
        if (i < 131072)      { lin = lin0; res = res0; dst = w0; p = 128; od = 512; }
        else if (i < 655360) { lin = lin1; res = res1; dst = w1; p = 512; od = 512; i -= 131072; }
        else if (i < 786432) { lin = lin2; res = res2; dst = w2; p = 512; od = 128; i -= 655360; }
        else return;
        int o = i / p, k = i - o * p;
        float v = (o < od) ? lin[(size_t)k * od + o] : res[(size_t)k * od + (o - od)];
        dst[i] = f2b(v);
    }
}

// ---------------- fused MFMA GEMM: [xl | rr] = A @ [linW | resW]^T, + per-head scores ----------------
// BM=128, BN=128 (of 2*od), BK=32, 4 waves, 4x4 frags (round-9/11 verified geometry).
// LAYER 0 (K=128): whole K staged into 4 LDS panels upfront -> ONE barrier, 4 barrier-free
// compute steps (removes 3 of 4 vmcnt(0)+barrier drains per block; short-K stall fix).
// LAYER 1/2: double-buffered 2-phase (unchanged, 818-820us verified).
template<int LAYER, int H>
__global__ __launch_bounds__(256) void gemm2_k(const u16* __restrict__ A, const u16* __restrict__ Bt,
                                               const float* __restrict__ res_b,
                                               const float* __restrict__ a_s, const float* __restrict__ a_d,
                                               u16* __restrict__ xl, u16* __restrict__ rr,
                                               float* __restrict__ ssrc, float* __restrict__ sdst,
                                               int M, int od, int K) {
    constexpr int NBUF = (LAYER == 0) ? 4 : 2;
    __shared__ __align__(16) u16 lds[NBUF][2][4096];  // [panel/buf][A/B][128 rows * 32 k]
    int tid = threadIdx.x;
    int nbx = od >> 6;                 // (2*od)/128 col blocks
    // bijective XCD swizzle (m204)
    int nwg = gridDim.x;
    int qq = nwg >> 3, r8 = nwg & 7;
    int xcd = blockIdx.x & 7, ii = blockIdx.x >> 3;
    int swz = (xcd < r8 ? xcd * (qq + 1) : r8 * (qq + 1) + (xcd - r8) * qq) + ii;
    int bx = swz % nbx, by = swz / nbx;
    int row0 = by << 7, col0 = bx << 7;
    int wave = tid >> 6, lane = tid & 63;
    int wm = (wave & 1) << 6, wn = (wave >> 1) << 6;
    int lr = lane & 15, q = lane >> 4;
    int lk8 = ((q ^ ((lr >> 1) & 3)) << 3);

    int schunk = ((tid & 3) ^ ((tid >> 3) & 3)) << 3;
    const u16* ga = A + (size_t)(row0 + (tid >> 2)) * K + schunk;
    const u16* gb = Bt + (size_t)(col0 + (tid >> 2)) * K + schunk;

    f32x4 acc[4][4];
#pragma unroll
    for (int mf = 0; mf < 4; ++mf)
#pragma unroll
        for (int nf = 0; nf < 4; ++nf) acc[mf][nf] = {0.f, 0.f, 0.f, 0.f};

    auto stage = [&](int buf, int k0) {
        char* la = (char*)&lds[buf][0][0] + (wave << 10);
        char* lb = (char*)&lds[buf][1][0] + (wave << 10);
        gload16(ga + k0, la);
        gload16(ga + k0 + (size_t)64 * K, la + 4096);
        gload16(gb + k0, lb);
        gload16(gb + k0 + (size_t)64 * K, lb + 4096);
    };

    auto compute = [&](const u16* La, const u16* Lb) {
        s16x8 af[4], bfr[4];
#pragma unroll
        for (int mf = 0; mf < 4; ++mf) af[mf] = *(const s16x8*)(La + (wm + mf * 16 + lr) * 32 + lk8);
#pragma unroll
        for (int nf = 0; nf < 4; ++nf) bfr[nf] = *(const s16x8*)(Lb + (wn + nf * 16 + lr) * 32 + lk8);
#pragma unroll
        for (int mf = 0; mf < 4; ++mf)
#pragma unroll
            for (int nf = 0; nf < 4; ++nf)
                acc[mf][nf] = __builtin_amdgcn_mfma_f32_16x16x32_bf16(bfr[nf], af[mf], acc[mf][nf], 0, 0, 0);
    };

    if constexpr (LAYER == 0) {
        // K=128: stage all 4 panels, one barrier, barrier-free compute
#pragma unroll
        for (int p4 = 0; p4 < 4; ++p4) stage(p4, p4 << 5);
        __syncthreads();
#pragma unroll
        for (int p4 = 0; p4 < 4; ++p4) compute((const u16*)lds[p4][0], (const u16*)lds[p4][1]);
        __syncthreads();   // seal LDS reads before sred reuse below
    } else {
        int nt = K >> 5;
        stage(0, 0);
        __syncthreads();
        int buf = 0;
        for (int t = 0; t < nt; ++t) {
            if (t + 1 < nt) stage(buf ^ 1, (t + 1) << 5);
            compute((const u16*)lds[buf][0], (const u16*)lds[buf][1]);
            __syncthreads();
            buf ^= 1;
        }
    }

    bool isRes = (col0 >= od);
    // ---- C write: row = row0+wm+mf*16+lr ; col = col0+wn+nf*16+q*4 (+0..3 packed) ----
#pragma unroll
    for (int mf = 0; mf < 4; ++mf) {
        int row = row0 + wm + mf * 16 + lr;
        if (row < M) {
            if (isRes) {
#pragma unroll
                for (int nf = 0; nf < 4; ++nf) {
                    int c = (col0 - od) + wn + nf * 16 + (q << 2);
                    float4 bv = *(const float4*)(res_b + c);
                    unsigned lo = (unsigned)f2b(acc[mf][nf][0] + bv.x) | ((unsigned)f2b(acc[mf][nf][1] + bv.y) << 16);
                    unsigned hi = (unsigned)f2b(acc[mf][nf][2] + bv.z) | ((unsigned)f2b(acc[mf][nf][3] + bv.w) << 16);
                    uint2 pk; pk.x = lo; pk.y = hi;
                    *(uint2*)(rr + (size_t)row * od + c) = pk;
                }
            } else {
#pragma unroll
                for (int nf = 0; nf < 4; ++nf) {
                    int c = col0 + wn + nf * 16 + (q << 2);
                    unsigned lo = (unsigned)f2b(acc[mf][nf][0]) | ((unsigned)f2b(acc[mf][nf][1]) << 16);
                    unsigned hi = (unsigned)f2b(acc[mf][nf][2]) | ((unsigned)f2b(acc[mf][nf][3]) << 16);
                    uint2 pk; pk.x = lo; pk.y = hi;
                    *(uint2*)(xl + (size_t)row * od + c) = pk;
                }
            }
        }
    }
    // ---- fused scores for lin blocks (block covers one full head of 128 cols) ----
    if (!isRes) {
        int hh = (H == 4) ? (col0 >> 7) : 0;
        const float* asb = a_s + hh * 128 + wn + (q << 2);
        const float* adb = a_d + hh * 128 + wn + (q << 2);
        float4 as4[4], ad4[4];
#pragma unroll
        for (int nf = 0; nf < 4; ++nf) {
            as4[nf] = *(const float4*)(asb + nf * 16);
            ad4[nf] = *(const float4*)(adb + nf * 16);
        }
        float* sred = (float*)&lds[0][0][0];  // K-loop done; sealed by barrier
#pragma unroll
        for (int mf = 0; mf < 4; ++mf) {
            float vs = 0.f, vd = 0.f;
#pragma unroll
            for (int nf = 0; nf < 4; ++nf) {
                vs += acc[mf][nf][0] * as4[nf].x + acc[mf][nf][1] * as4[nf].y
                    + acc[mf][nf][2] * as4[nf].z + acc[mf][nf][3] * as4[nf].w;
                vd += acc[mf][nf][0] * ad4[nf].x + acc[mf][nf][1] * ad4[nf].y
                    + acc[mf][nf][2] * ad4[nf].z + acc[mf][nf][3] * ad4[nf].w;
            }
            vs += __shfl_xor(vs, 16); vs += __shfl_xor(vs, 32);
            vd += __shfl_xor(vd, 16); vd += __shfl_xor(vd, 32);
            if (q == 0) {
                int rl = wm + mf * 16 + lr;
                sred[(wn >> 6) * 256 + rl * 2 + 0] = vs;
                sred[(wn >> 6) * 256 + rl * 2 + 1] = vd;
            }
        }
        __syncthreads();
        int rl = tid >> 1, which = tid & 1;
        int grow = row0 + rl;
        if (grow < M) {
            float v = sred[rl * 2 + which] + sred[256 + rl * 2 + which];
            if (which == 0) ssrc[grow * H + hh] = v;
            else            sdst[grow * H + hh] = v;
        }
    }
}

// ---------------- CSR build ----------------
__global__ void bsum_k(const int* __restrict__ cnt, int* __restrict__ bsum) {
    __shared__ int sd[256];
    int t = threadIdx.x, i = blockIdx.x * 256 + t;
    sd[t] = (i < N) ? cnt[i] : 0;
    __syncthreads();
    for (int off = 128; off; off >>= 1) { if (t < off) sd[t] += sd[t + off]; __syncthreads(); }
    if (t == 0) bsum[blockIdx.x] = sd[0];
}

// block 0: exclusive scan of per-block sums ; block 1: group counts via binary search
__global__ void scan2_k(const int* __restrict__ bsum, int* __restrict__ boff, int nb,
                        const int* __restrict__ batch, int* __restrict__ cntg) {
    if (blockIdx.x == 0) {
        __shared__ int sd[256];
        int t = threadIdx.x;
        int v = (t < nb) ? bsum[t] : 0;
        sd[t] = v;
        __syncthreads();
        for (int off = 1; off < 256; off <<= 1) {
            int tmp = (t >= off) ? sd[t - off] : 0;
            __syncthreads();
            sd[t] += tmp;
            __syncthreads();
        }
        if (t < nb) boff[t] = sd[t] - v;  // exclusive
    } else {
        int g = threadIdx.x;
        if (g >= G) return;
        int lo = 0, hi = N;
        while (lo < hi) { int mid = (lo + hi) >> 1; if (batch[mid] < g) lo = mid + 1; else hi = mid; }
        int lb0 = lo;
        lo = 0; hi = N;
        while (lo < hi) { int mid = (lo + hi) >> 1; if (batch[mid] < g + 1) lo = mid + 1; else hi = mid; }
        cntg[g] = lo - lb0;
    }
}

// per-block inclusive scan + block offset; writes indptr (inclusive at i+1) and fill (exclusive at i)
__global__ void iscan_k(const int* __restrict__ cnt, const int* __restrict__ boff,
                        int* __restrict__ indptr, int* __restrict__ fill) {
    __shared__ int sd[256];
    int b = blockIdx.x, t = threadIdx.x, i = b * 256 + t;
    int v = (i < N) ? cnt[i] : 0;
    sd[t] = v;
    __syncthreads();
    for (int off = 1; off < 256; off <<= 1) {
        int tmp = (t >= off) ? sd[t - off] : 0;
        __syncthreads();
        sd[t] += tmp;
        __syncthreads();
    }
    if (i < N) {
        int incl = boff[b] + sd[t];
        indptr[i + 1] = incl;
        fill[i] = incl - v;
    }
    if (i == 0) indptr[0] = 0;
}

__global__ void scatter_k(const int* __restrict__ ei, int* __restrict__ fill, int* __restrict__ out, int E, int ET) {
    int e = blockIdx.x * 256 + threadIdx.x;
    if (e >= ET) return;
    int s, d;
    if (e < E) { s = ei[e]; d = ei[E + e]; } else { s = d = e - E; }
    int pos = atomicAdd(&fill[d], 1);
    out[pos] = s;
}

// ---------------- GAT aggregation + bias/BN/relu + residual add (h_next in-place into rr) ----------------
// online-softmax single gather pass; pass-3 row-gather unrolled x4.
template<int H, int OD>
__global__ __launch_bounds__(256) void agg_k(const u16* __restrict__ xl, const float* __restrict__ ssrc,
                                             const float* __restrict__ sdst, const int* __restrict__ indptr,
                                             const int* __restrict__ srcs, const float* __restrict__ bias,
                                             const float* __restrict__ bng, const float* __restrict__ bnb,
                                             const float* __restrict__ bnm, const float* __restrict__ bnv,
                                             u16* __restrict__ rr) {
    int w = (blockIdx.x * 256 + threadIdx.x) >> 6;
    int lane = threadIdx.x & 63;
    if (w >= N) return;
    int beg = indptr[w], deg = indptr[w + 1] - beg;
    constexpr int GRP = (H == 4) ? 16 : 64;
    int h = (H == 4) ? (lane >> 4) : 0;
    float sdl = sdst[w * H + h];
    float lmax = -3.4e38f, lsum = 0.f;
    int sub = lane & (GRP - 1);
    for (int e = sub; e < deg; e += GRP) {
        int s = srcs[beg + e];
        float v = ssrc[s * H + h] + sdl;
        v = v > 0.f ? v : 0.2f * v;
        if (v > lmax) {
            lsum = lsum * __expf(lmax - v) + 1.0f;
            lmax = v;
        } else {
            lsum += __expf(v - lmax);
        }
    }
#pragma unroll
    for (int o = GRP >> 1; o; o >>= 1) {
        float mo = __shfl_xor(lmax, o);
        float so = __shfl_xor(lsum, o);
        float mn = fmaxf(lmax, mo);
        lsum = lsum * __expf(lmax - mn) + so * __expf(mo - mn);
        lmax = mn;
    }
    float inv = 1.0f / lsum;

    constexpr int EPL = OD / 64;
    float acc[EPL];
#pragma unroll
    for (int j = 0; j < EPL; ++j) acc[j] = 0.f;
    int e = 0;
    for (; e + 4 <= deg; e += 4) {
        int s0 = srcs[beg + e], s1 = srcs[beg + e + 1];
        int s2 = srcs[beg + e + 2], s3 = srcs[beg + e + 3];
        float v0 = ssrc[s0 * H + h] + sdl;
        float v1 = ssrc[s1 * H + h] + sdl;
        float v2 = ssrc[s2 * H + h] + sdl;
        float v3 = ssrc[s3 * H + h] + sdl;
        v0 = v0 > 0.f ? v0 : 0.2f * v0;
        v1 = v1 > 0.f ? v1 : 0.2f * v1;
        v2 = v2 > 0.f ? v2 : 0.2f * v2;
        v3 = v3 > 0.f ? v3 : 0.2f * v3;
        float wg0 = __expf(v0 - lmax) * inv;
        float wg1 = __expf(v1 - lmax) * inv;
        float wg2 = __expf(v2 - lmax) * inv;
        float wg3 = __expf(v3 - lmax) * inv;
        if constexpr (EPL == 8) {
            s16x8 xv0 = *(const s16x8*)(xl + (size_t)s0 * OD + lane * 8);
            s16x8 xv1 = *(const s16x8*)(xl + (size_t)s1 * OD + lane * 8);
            s16x8 xv2 = *(const s16x8*)(xl + (size_t)s2 * OD + lane * 8);
            s16x8 xv3 = *(const s16x8*)(xl + (size_t)s3 * OD + lane * 8);
#pragma unroll
            for (int j = 0; j < 8; ++j) acc[j] += b2f((u16)xv0[j]) * wg0;
#pragma unroll
            for (int j = 0; j < 8; ++j) acc[j] += b2f((u16)xv1[j]) * wg1;
#pragma unroll
            for (int j = 0; j < 8; ++j) acc[j] += b2f((u16)xv2[j]) * wg2;
#pragma unroll
            for (int j = 0; j < 8; ++j) acc[j] += b2f((u16)xv3[j]) * wg3;
        } else {
            unsigned xv0 = *(const unsigned*)(xl + (size_t)s0 * OD + lane * 2);
            unsigned xv1 = *(const unsigned*)(xl + (size_t)s1 * OD + lane * 2);
            unsigned xv2 = *(const unsigned*)(xl + (size_t)s2 * OD + lane * 2);
            unsigned xv3 = *(const unsigned*)(xl + (size_t)s3 * OD + lane * 2);
            acc[0] += b2f((u16)(xv0 & 0xffff)) * wg0 + b2f((u16)(xv1 & 0xffff)) * wg1
                    + b2f((u16)(xv2 & 0xffff)) * wg2 + b2f((u16)(xv3 & 0xffff)) * wg3;
            acc[1] += b2f((u16)(xv0 >> 16)) * wg0 + b2f((u16)(xv1 >> 16)) * wg1
                    + b2f((u16)(xv2 >> 16)) * wg2 + b2f((u16)(xv3 >> 16)) * wg3;
        }
    }
    for (; e < deg; ++e) {
        int s = srcs[beg + e];
        float v = ssrc[s * H + h] + sdl;
        v = v > 0.f ? v : 0.2f * v;
        float wg = __expf(v - lmax) * inv;
        if constexpr (EPL == 8) {
            s16x8 xv = *(const s16x8*)(xl + (size_t)s * OD + lane * 8);
#pragma unroll
            for (int j = 0; j < 8; ++j) acc[j] += b2f((u16)xv[j]) * wg;
        } else {
            unsigned xv = *(const unsigned*)(xl + (size_t)s * OD + lane * 2);
            acc[0] += b2f((u16)(xv & 0xffff)) * wg;
            acc[1] += b2f((u16)(xv >> 16)) * wg;
        }
    }
    if constexpr (EPL == 8) {
        s16x8 rv = *(const s16x8*)(rr + (size_t)w * OD + lane * 8);
        s16x8 ov;
#pragma unroll
        for (int j = 0; j < 8; ++j) {
            int c = lane * 8 + j;
            float v = acc[j] + bias[c] - bnm[c];
            v = v * rsqrtf(bnv[c] + 1e-5f) * bng[c] + bnb[c];
            ov[j] = (short)f2b(b2f((u16)rv[j]) + fmaxf(v, 0.f));
        }
        *(s16x8*)(rr + (size_t)w * OD + lane * 8) = ov;
    } else {
        unsigned rv = *(const unsigned*)(rr + (size_t)w * OD + lane * 2);
        unsigned o01 = 0;
#pragma unroll
        for (int j = 0; j < 2; ++j) {
            int c = lane * 2 + j;
            float v = acc[j] + bias[c] - bnm[c];
            v = v * rsqrtf(bnv[c] + 1e-5f) * bng[c] + bnb[c];
            float hv = b2f((u16)((rv >> (16 * j)) & 0xffff)) + fmaxf(v, 0.f);
            o01 |= ((unsigned)f2b(hv)) << (16 * j);
        }
        *(unsigned*)(rr + (size_t)w * OD + lane * 2) = o01;
    }
}

// ---------------- pooling ----------------
__device__ inline unsigned fkey(float f) {
    unsigned u = __float_as_uint(f);
    return (u & 0x80000000u) ? ~u : (u | 0x80000000u);
}

__global__ __launch_bounds__(128) void pool_k(const u16* __restrict__ h, const int* __restrict__ batch,
                                              float* __restrict__ psum, unsigned* __restrict__ pmax) {
    int c = threadIdx.x;
    int n0 = blockIdx.x * 64;
    if (n0 >= N) return;
    int nend = min(n0 + 64, N);
    int cur = batch[n0];
    float acc = 0.f, mx = -3.4e38f;
    for (int i = n0; i < nend; ++i) {
        int g = batch[i];
        if (g != cur) {
            atomicAdd(&psum[cur * 128 + c], acc);
            atomicMax(&pmax[cur * 128 + c], fkey(mx));
            acc = 0.f; mx = -3.4e38f; cur = g;
        }
        float v = b2f(h[(size_t)i * 128 + c]);
        acc += v;
        mx = fmaxf(mx, v);
    }
    atomicAdd(&psum[cur * 128 + c], acc);
    atomicMax(&pmax[cur * 128 + c], fkey(mx));
}

// ---------------- head: g=[mean,max] -> relu(g@W+b) -> LayerNorm (f32 out), 768 threads ----------------
__global__ __launch_bounds__(768) void head_k(const float* __restrict__ psum, const unsigned* __restrict__ pmax,
                                              const int* __restrict__ cntg, const float* __restrict__ W,
                                              const float* __restrict__ b, const float* __restrict__ lng,
                                              const float* __restrict__ lnb, float* __restrict__ out) {
    __shared__ float gin[256];
    __shared__ float red[768];
    int g = blockIdx.x, t = threadIdx.x;
    int cg = cntg[g];
    if (t < 256) {
        float val;
        if (t < 128) {
            val = psum[g * 128 + t] / fmaxf((float)cg, 1.0f);
        } else {
            unsigned k = pmax[g * 128 + (t - 128)];
            if (cg > 0 && k != 0u) {
                unsigned u = (k & 0x80000000u) ? (k ^ 0x80000000u) : ~k;
                val = __uint_as_float(u);
            } else val = 0.0f;
        }
        gin[t] = val;
    }
    __syncthreads();
    float s = b[t];
    for (int k = 0; k < 256; ++k) s += gin[k] * W[(size_t)k * OUT + t];
    float z = fmaxf(s, 0.f);
    red[t] = z;
    __syncthreads();
    if (t < 256) red[t] = red[t] + red[t + 256] + red[t + 512];
    __syncthreads();
    for (int off = 128; off; off >>= 1) { if (t < off) red[t] += red[t + off]; __syncthreads(); }
    float mu = red[0] / 768.0f;
    __syncthreads();
    float d = z - mu;
    red[t] = d * d;
    __syncthreads();
    if (t < 256) red[t] = red[t] + red[t + 256] + red[t + 512];
    __syncthreads();
    for (int off = 128; off; off >>= 1) { if (t < off) red[t] += red[t + off]; __syncthreads(); }
    float inv = rsqrtf(red[0] / 768.0f + 1e-5f);
    out[(size_t)g * OUT + t] = d * inv * lng[t] + lnb[t];
}

extern "C" void kernel_launch(void* const* d_in, const int* in_sizes, int n_in,
                              void* d_out, int out_size, void* d_ws, size_t ws_size,
                              hipStream_t stream) {
    const float* x = (const float*)d_in[0];
    const int* node_ids = (const int*)d_in[1];
    const int* ei = (const int*)d_in[2];
    const int* batch = (const int*)d_in[3];
    const float* emb = (const float*)d_in[4];
    const float* in_W = (const float*)d_in[5];
    const float* in_b = (const float*)d_in[6];
    const float* L[3][10];
    for (int l = 0; l < 3; ++l)
        for (int q = 0; q < 10; ++q) L[l][q] = (const float*)d_in[7 + l * 10 + q];
    const float* out_W = (const float*)d_in[37];
    const float* out_b = (const float*)d_in[38];
    const float* ln_g = (const float*)d_in[39];
    const float* ln_b = (const float*)d_in[40];
    int E = in_sizes[2] / 2;
    int ET = E + N;
    const int NBLK = (N + 255) / 256;   // 196

    char* ws = (char*)d_ws;
    size_t off = 0;
    auto alloc = [&](size_t bytes) -> void* {
        void* p = ws + off;
        off += (bytes + 255) & ~(size_t)255;
        return p;
    };
    const size_t NBH = (size_t)MPAD * 512 * sizeof(u16);
    u16* bufA = (u16*)alloc(NBH);
    u16* bufB = (u16*)alloc(NBH);
    u16* bufC = (u16*)alloc(NBH);
    const int lp[3] = {128, 512, 512};
    const int lod[3] = {512, 512, 128};
    u16* wcomb[3];
    for (int l = 0; l < 3; ++l) wcomb[l] = (u16*)alloc((size_t)2 * lod[l] * lp[l] * sizeof(u16));
    float* ssrc = (float*)alloc((size_t)N * 4 * sizeof(float));
    float* sdst = (float*)alloc((size_t)N * 4 * sizeof(float));
    int* cnt = (int*)alloc((size_t)N * sizeof(int));
    int* indptr = (int*)alloc((size_t)(N + 1) * sizeof(int));
    int* fill = (int*)alloc((size_t)N * sizeof(int));
    int* ssorted = (int*)alloc((size_t)ET * sizeof(int));
    int* bsum = (int*)alloc(256 * sizeof(int));
    int* boff = (int*)alloc(256 * sizeof(int));
    float* psum = (float*)alloc(G * 128 * sizeof(float));
    unsigned* pmax = (unsigned*)alloc(G * 128 * sizeof(unsigned));
    int* cntg = (int*)alloc(G * sizeof(int));

    if (off > ws_size) return;  // clean diagnostic failure instead of OOB fault

    hipMemsetAsync(cnt, 0, (size_t)N * sizeof(int), stream);
    hipMemsetAsync(psum, 0, G * 128 * sizeof(float), stream);
    hipMemsetAsync(pmax, 0, G * 128 * sizeof(unsigned), stream);

    // fused prep: input transform ∥ edge count ∥ weight cvt (3072 blocks of cvt)
    int nbCnt = (ET + 255) / 256;
    prep_k<<<25000 + nbCnt + 3072, 256, 0, stream>>>(x, node_ids, emb, in_W, in_b, bufA,
                                                     ei, cnt, E, ET, nbCnt,
                                                     L[0][0], L[0][8], wcomb[0],
                                                     L[1][0], L[1][8], wcomb[1],
                                                     L[2][0], L[2][8], wcomb[2]);
    bsum_k<<<NBLK, 256, 0, stream>>>(cnt, bsum);
    scan2_k<<<2, 256, 0, stream>>>(bsum, boff, NBLK, batch, cntg);
    iscan_k<<<NBLK, 256, 0, stream>>>(cnt, boff, indptr, fill);
    scatter_k<<<(ET + 255) / 256, 256, 0, stream>>>(ei, fill, ssorted, E, ET);

    u16* h = bufA;
    u16* xb = bufB;
    u16* rb = bufC;
    const int nby = MPAD >> 7;  // 391
    for (int l = 0; l < 3; ++l) {
        int p = lp[l], od = lod[l];
        int nbx = od >> 6;
        int grid = nbx * nby;
        if (l == 0)
            gemm2_k<0, 4><<<grid, 256, 0, stream>>>(h, wcomb[l], L[l][9], L[l][1], L[l][2],
                                                    xb, rb, ssrc, sdst, N, od, p);
        else if (l == 1)
            gemm2_k<1, 4><<<grid, 256, 0, stream>>>(h, wcomb[l], L[l][9], L[l][1], L[l][2],
                                                    xb, rb, ssrc, sdst, N, od, p);
        else
            gemm2_k<2, 1><<<grid, 256, 0, stream>>>(h, wcomb[l], L[l][9], L[l][1], L[l][2],
                                                    xb, rb, ssrc, sdst, N, od, p);
        int sblocks = ((size_t)N * 64 + 255) / 256;
        if (l < 2)
            agg_k<4, 512><<<sblocks, 256, 0, stream>>>(xb, ssrc, sdst, indptr, ssorted,
                                                       L[l][3], L[l][4], L[l][5], L[l][6], L[l][7], rb);
        else
            agg_k<1, 128><<<sblocks, 256, 0, stream>>>(xb, ssrc, sdst, indptr, ssorted,
                                                       L[l][3], L[l][4], L[l][5], L[l][6], L[l][7], rb);
        // h_next now lives in rb; rotate buffers
        u16* t2 = h; h = rb; rb = xb; xb = t2;
    }

    pool_k<<<(N + 63) / 64, 128, 0, stream>>>(h, batch, psum, pmax);
    head_k<<<G, 768, 0, stream>>>(psum, pmax, cntg, out_W, out_b, ln_g, ln_b, (float*)d_out);
}